// Round 8
// baseline (766.464 us; speedup 1.0000x reference)
//
#include <hip/hip_runtime.h>
#include <math.h>

// Problem constants
constexpr int BATCH = 4;
constexpr int SEQ   = 4096;
constexpr int DIMC  = 512;
constexpr int NH    = 8;
constexpr int HD    = 64;
constexpr int NLM   = 256;   // landmarks M
constexpr int LWIN  = 16;    // SEQ / NLM
constexpr int KWIN  = 33;
constexpr int BH    = BATCH * NH; // 32

typedef __attribute__((ext_vector_type(8))) short  bfrag;  // 8 bf16 for MFMA A/B
typedef __attribute__((ext_vector_type(4))) float  ffrag;  // MFMA C/D
typedef __attribute__((ext_vector_type(8))) unsigned short us8;
typedef __attribute__((ext_vector_type(4))) unsigned short us4;
typedef unsigned short ush;

__device__ __forceinline__ ush f2bf(float f) {
  unsigned u = __builtin_bit_cast(unsigned, f);
  return (ush)((u + 0x7FFFu + ((u >> 16) & 1u)) >> 16);
}
__device__ __forceinline__ float bf2f(ush h) {
  unsigned u = ((unsigned)h) << 16;
  return __builtin_bit_cast(float, u);
}
__device__ __forceinline__ void splitf(float f, ush& h, ush& l) {
  h = f2bf(f);
  l = f2bf(f - bf2f(h));
}
// async global->LDS, 16B per lane: LDS dest = base + lane*16 (wave-uniform base)
__device__ __forceinline__ void gl_lds16(const ush* g, ush* l) {
  __builtin_amdgcn_global_load_lds(
      (const __attribute__((address_space(1))) void*)g,
      (__attribute__((address_space(3))) void*)l, 16, 0, 0);
}

// ---------------------------------------------------------------------------
// split_flat: fp32 -> (hi, lo) bf16, elementwise (x pre-split). Grid-stride.
// ---------------------------------------------------------------------------
__global__ void split_flat(const float* __restrict__ src, ush* __restrict__ oh,
                           ush* __restrict__ ol, int n4) {
  for (int i = blockIdx.x * 256 + threadIdx.x; i < n4; i += gridDim.x * 256) {
    float4 f = ((const float4*)src)[i];
    us4 h, l;
    float fs[4] = {f.x, f.y, f.z, f.w};
#pragma unroll
    for (int j = 0; j < 4; ++j) {
      ush hh, ll;
      splitf(fs[j], hh, ll);
      h[j] = hh; l[j] = ll;
    }
    ((us4*)oh)[i] = h;
    ((us4*)ol)[i] = l;
  }
}

// ---------------------------------------------------------------------------
// transpose_split_w: in [R][C] fp32 -> out [C][R] hi/lo bf16 (weights)
// ---------------------------------------------------------------------------
__global__ __launch_bounds__(256) void transpose_split_w(const float* __restrict__ in,
                                                         ush* __restrict__ oh,
                                                         ush* __restrict__ ol,
                                                         int R, int C) {
  __shared__ float T[32][33];
  const int tid = threadIdx.x;
  const int c0 = blockIdx.x * 32, r0 = blockIdx.y * 32;
#pragma unroll
  for (int u = 0; u < 4; ++u) {
    int r = (tid >> 5) * 4 + u, cl = tid & 31;
    T[r][cl] = in[(size_t)(r0 + r) * C + c0 + cl];
  }
  __syncthreads();
#pragma unroll
  for (int u = 0; u < 4; ++u) {
    int cl = (tid >> 5) * 4 + u, rl = tid & 31;
    float f = T[rl][cl];
    ush h, l; splitf(f, h, l);
    size_t o = (size_t)(c0 + cl) * R + r0 + rl;
    oh[o] = h; ol[o] = l;
  }
}

// ---------------------------------------------------------------------------
// K1: qkv MFMA GEMM — ROUND-8: gl_lds staging at m97 GEOMETRY (BK=64,
// 12 issues/wave/barrier, 64 MFMA/barrier, 8 k-iters). r7's BK=32 variant
// (6 issues/wave, 32 MFMA/barrier) was latency-bound: conflicts 0 but
// HBM 841 GB/s, MfmaUtil 15%. LDS 48 KB -> 3 blocks/CU (m97's occupancy).
// 2-product split (x split, W hi-only). Epilogue: q/k + landmarks; vT direct.
// ---------------------------------------------------------------------------
__global__ __launch_bounds__(256) void qkv_mfma(const ush* __restrict__ xh,
                                                const ush* __restrict__ xl,
                                                const ush* __restrict__ wTh,
                                                ush* __restrict__ q_bf,
                                                ush* __restrict__ k_bf,
                                                ush* __restrict__ vT,
                                                float* __restrict__ qlm,
                                                float* __restrict__ klm) {
  __shared__ ush S[3][8][128][8];   // 48 KB: planes {xh, xl, wTh}, BK=64
  const int tid = threadIdx.x;
  const int w = tid >> 6, lane = tid & 63;
  const int lm = lane & 15, lq = lane >> 4;
  const int wm = w >> 1, wn = w & 1;
  const int row0 = blockIdx.x * 128, col0 = blockIdx.y * 128;
  const ffrag fz = {0.f, 0.f, 0.f, 0.f};
  ffrag acc[4][4];
#pragma unroll
  for (int i = 0; i < 4; ++i)
#pragma unroll
    for (int j = 0; j < 4; ++j) acc[i][j] = fz;

  for (int k0 = 0; k0 < 512; k0 += 64) {
    __syncthreads();
    // 48 DMA issues: item = (plane p, chunk ch 0..7, half hf); wave w takes 12.
#pragma unroll
    for (int it2 = 0; it2 < 12; ++it2) {
      int item = 12 * w + it2;
      int p = item >> 4, ch = (item >> 1) & 7, hf = item & 1;
      const ush* g = (p == 0) ? xh : ((p == 1) ? xl : wTh);
      int rb = (p == 2) ? col0 : row0;
      gl_lds16(&g[(size_t)(rb + hf * 64 + lane) * 512 + k0 + 8 * ch],
               &S[p][ch][hf * 64][0]);
    }
    __syncthreads();   // vmcnt(0) drain (m97 structure)
#pragma unroll
    for (int ks = 0; ks < 2; ++ks) {
      bfrag ah[4], al[4], bh[4];
#pragma unroll
      for (int mt = 0; mt < 4; ++mt) {
        ah[mt] = *(const bfrag*)&S[0][4 * ks + lq][64 * wm + 16 * mt + lm][0];
        al[mt] = *(const bfrag*)&S[1][4 * ks + lq][64 * wm + 16 * mt + lm][0];
      }
#pragma unroll
      for (int nt = 0; nt < 4; ++nt)
        bh[nt] = *(const bfrag*)&S[2][4 * ks + lq][64 * wn + 16 * nt + lm][0];
#pragma unroll
      for (int mt = 0; mt < 4; ++mt)
#pragma unroll
        for (int nt = 0; nt < 4; ++nt) {
          acc[mt][nt] = __builtin_amdgcn_mfma_f32_16x16x32_bf16(ah[mt], bh[nt], acc[mt][nt], 0, 0, 0);
          acc[mt][nt] = __builtin_amdgcn_mfma_f32_16x16x32_bf16(al[mt], bh[nt], acc[mt][nt], 0, 0, 0);
        }
    }
  }
  // epilogue (unchanged, r4-r7 verified)
#pragma unroll
  for (int mt = 0; mt < 4; ++mt) {
    int rbase = row0 + 64 * wm + 16 * mt;      // 16-aligned -> single window
    int b = rbase >> 12;
    int ntok_base = rbase & 4095;
    int win = ntok_base >> 4;
#pragma unroll
    for (int nt = 0; nt < 4; ++nt) {
      int n_local = 64 * wn + 16 * nt;          // frag col base (h uniform)
      int col = col0 + n_local + lm;
      int which = col >> 9;                     // 0=q 1=k 2=v
      int h = (col >> 6) & 7;
      int d = col & 63;
      int bh_i = b * NH + h;
      float scale = (which == 0) ? 0.125f : 1.0f;
      float vals[4];
      float s = 0.f;
#pragma unroll
      for (int r = 0; r < 4; ++r) {
        vals[r] = acc[mt][nt][r] * scale;
        s += vals[r];
      }
      if (which == 2) {
        ush* dst = &vT[((size_t)bh_i * HD + d) * SEQ + ntok_base + 4 * lq];
#pragma unroll
        for (int r = 0; r < 4; ++r) dst[r] = f2bf(vals[r]);
      } else {
        ush* dst = which == 0 ? q_bf : k_bf;
#pragma unroll
        for (int r = 0; r < 4; ++r) {
          int ntok = ntok_base + 4 * lq + r;
          dst[((size_t)bh_i * SEQ + ntok) * HD + d] = f2bf(vals[r]);
        }
        s += __shfl_xor(s, 16);
        s += __shfl_xor(s, 32);
        if (lq == 0) {
          float* lmdst = which == 0 ? qlm : klm;
          lmdst[((size_t)bh_i * NLM + win) * HD + d] = s * (1.0f / LWIN);
        }
      }
    }
  }
}

// ---------------------------------------------------------------------------
// K3: attn2 = softmax(qlm @ klm^T) rows -> split bf16 (a2h/a2l)
// ---------------------------------------------------------------------------
__global__ __launch_bounds__(256) void sim2_softmax(const float* __restrict__ qlm,
                                                    const float* __restrict__ klm,
                                                    ush* __restrict__ a2h,
                                                    ush* __restrict__ a2l) {
  int i = blockIdx.x & 255;
  int bh = blockIdx.x >> 8;
  int j = threadIdx.x;
  __shared__ float qrow[64];
  __shared__ float red[256];
  if (j < 64) qrow[j] = qlm[((size_t)bh * NLM + i) * HD + j];
  __syncthreads();
  const float* kr = klm + ((size_t)bh * NLM + j) * HD;
  float s = 0.f;
#pragma unroll
  for (int d = 0; d < 64; d += 4) {
    float4 kv = *(const float4*)&kr[d];
    s += qrow[d] * kv.x + qrow[d + 1] * kv.y + qrow[d + 2] * kv.z + qrow[d + 3] * kv.w;
  }
  red[j] = s; __syncthreads();
  for (int off = 128; off > 0; off >>= 1) {
    if (j < off) red[j] = fmaxf(red[j], red[j + off]);
    __syncthreads();
  }
  float mx = red[0]; __syncthreads();
  float e = expf(s - mx);
  red[j] = e; __syncthreads();
  for (int off = 128; off > 0; off >>= 1) {
    if (j < off) red[j] += red[j + off];
    __syncthreads();
  }
  float val = e / red[0];
  size_t o = ((size_t)bh * NLM + i) * NLM + j;
  ush h, l; splitf(val, h, l);
  a2h[o] = h; a2l[o] = l;
}

// ---------------------------------------------------------------------------
// K4a: per-bh column sums of attn2 (hi plane only), block max.
// attn2 rows are softmax rows -> row sums are exactly 1.
// ---------------------------------------------------------------------------
__global__ __launch_bounds__(256) void colmax(const ush* __restrict__ a2h,
                                              float* __restrict__ red) {
  int bh = blockIdx.x;
  int t = threadIdx.x;
  const size_t base = (size_t)bh * NLM * NLM;
  float cs = 0.f;
  for (int i = 0; i < NLM; ++i) cs += bf2f(a2h[base + (size_t)i * NLM + t]);
  __shared__ float r1[256];
  r1[t] = cs; __syncthreads();
  for (int off = 128; off > 0; off >>= 1) {
    if (t < off) r1[t] = fmaxf(r1[t], r1[t + off]);
    __syncthreads();
  }
  if (t == 0) red[bh] = r1[0];
}

__global__ void finalize_scale(float* __restrict__ red) {
  if (threadIdx.x == 0) {
    float m1 = -1e30f;
    for (int i = 0; i < BH; ++i) m1 = fmaxf(m1, red[i]);
    red[64] = 1.0f / m1;   // row-sum max == 1 exactly (softmax rows)
  }
}

// ---------------------------------------------------------------------------
// K4c: z0 = attn2^T * invscale, A-form + B-form splits
// ---------------------------------------------------------------------------
__global__ __launch_bounds__(256) void zinit_split(const ush* __restrict__ a2h,
                                                   const ush* __restrict__ a2l,
                                                   const float* __restrict__ red,
                                                   ush* __restrict__ zAh, ush* __restrict__ zAl,
                                                   ush* __restrict__ zBh, ush* __restrict__ zBl) {
  __shared__ float T[32][33];
  const int tid = threadIdx.x;
  const int bh = blockIdx.z;
  const int j0 = blockIdx.x * 32, i0 = blockIdx.y * 32;
  const float s = red[64];
  const size_t base = (size_t)bh * NLM * NLM;
#pragma unroll
  for (int u = 0; u < 4; ++u) {
    int jl = (tid >> 5) * 4 + u, il = tid & 31;
    size_t o = base + (size_t)(j0 + jl) * NLM + i0 + il;
    float a = (bf2f(a2h[o]) + bf2f(a2l[o])) * s;
    T[jl][il] = a;
    ush h, l; splitf(a, h, l);
    zBh[o] = h; zBl[o] = l;   // zB[j][i] = a2[j][i]*s
  }
  __syncthreads();
#pragma unroll
  for (int u = 0; u < 4; ++u) {
    int il = (tid >> 5) * 4 + u, jl = tid & 31;
    float a = T[jl][il];
    ush h, l; splitf(a, h, l);
    size_t o = base + (size_t)(i0 + il) * NLM + j0 + jl;  // zA[i][j] = a2[j][i]*s
    zAh[o] = h; zAl[o] = l;
  }
}

// ---------------------------------------------------------------------------
// K5 core: one 64x64 tile of C = A@B^T(stored) with split-bf16 planes.
// m97 structure: global_load_lds staging, BK=64. Null lo-pointers skip planes.
// Epilogue: y = coef * (alpha*E1 + beta*E2 - C); outputs row-major (oA),
// transposed B-form (oB), and optional RAW C (oC, hi bf16 row-major — the
// carry-Y tap). FORCEINLINE ONLY (noinline corrupted global_load_lds -> r2).
// NOTE (r4/r5): in-kernel barrier fusion is structurally HBM-bound — never
// re-fuse.
// ---------------------------------------------------------------------------
__device__ __forceinline__ void stage_gemm(
    ush (*S)[2][8][64][8],   // LDS [2][2][8][64][8] = 32 KB
    const ush* Ah, const ush* Al, const ush* Bh, const ush* Bl,
    const ush* E1h, const ush* E1l, const ush* E2h, const ush* E2l,
    ush* oAh, ush* oAl, ush* oBh, ush* oBl, ush* oCh,
    int M, int N, int K, float alpha, float beta, float coef,
    int bx, int by, int batch, int tid) {
  const size_t abase = (size_t)batch * M * K;
  const size_t bbase = (size_t)batch * N * K;
  const size_t ebase = (size_t)batch * M * N;
  const int w = tid >> 6, lane = tid & 63;
  const int lm = lane & 15, lq = lane >> 4;
  const int wm = w >> 1, wn = w & 1;
  const int row0 = bx * 64, col0 = by * 64;
  const bool uAl = (Al != nullptr);
  const bool uBl = (Bl != nullptr);
  const ffrag fz = {0.f, 0.f, 0.f, 0.f};
  ffrag acc[2][2] = {{fz, fz}, {fz, fz}};

  const size_t arow = abase + (size_t)(row0 + lane) * K;   // per-lane
  const size_t brow = bbase + (size_t)(col0 + lane) * K;

  for (int k0 = 0; k0 < K; k0 += 64) {
    __syncthreads();
    // wave w stages k-chunks {2w, 2w+1} for A and B (lo planes only if used)
#pragma unroll
    for (int ci = 0; ci < 2; ++ci) {
      int c = 2 * w + ci;
      gl_lds16(&Ah[arow + k0 + 8 * c], &S[0][0][c][0][0]);
      gl_lds16(&Bh[brow + k0 + 8 * c], &S[1][0][c][0][0]);
      if (uAl) gl_lds16(&Al[arow + k0 + 8 * c], &S[0][1][c][0][0]);
      if (uBl) gl_lds16(&Bl[brow + k0 + 8 * c], &S[1][1][c][0][0]);
    }
    __syncthreads();   // compiler emits vmcnt(0) drain here (m97 structure)
#pragma unroll
    for (int ks = 0; ks < 2; ++ks) {
      bfrag ah[2], al[2], bhf[2], blf[2];
#pragma unroll
      for (int mt = 0; mt < 2; ++mt) {
        ah[mt] = *(const bfrag*)&S[0][0][4 * ks + lq][32 * wm + 16 * mt + lm][0];
        if (uAl) al[mt] = *(const bfrag*)&S[0][1][4 * ks + lq][32 * wm + 16 * mt + lm][0];
      }
#pragma unroll
      for (int nt = 0; nt < 2; ++nt) {
        bhf[nt] = *(const bfrag*)&S[1][0][4 * ks + lq][32 * wn + 16 * nt + lm][0];
        if (uBl) blf[nt] = *(const bfrag*)&S[1][1][4 * ks + lq][32 * wn + 16 * nt + lm][0];
      }
#pragma unroll
      for (int mt = 0; mt < 2; ++mt)
#pragma unroll
        for (int nt = 0; nt < 2; ++nt) {
          acc[mt][nt] = __builtin_amdgcn_mfma_f32_16x16x32_bf16(ah[mt], bhf[nt], acc[mt][nt], 0, 0, 0);
          if (uAl) acc[mt][nt] = __builtin_amdgcn_mfma_f32_16x16x32_bf16(al[mt], bhf[nt], acc[mt][nt], 0, 0, 0);
          if (uBl) acc[mt][nt] = __builtin_amdgcn_mfma_f32_16x16x32_bf16(ah[mt], blf[nt], acc[mt][nt], 0, 0, 0);
        }
    }
  }
#pragma unroll
  for (int mt = 0; mt < 2; ++mt)
#pragma unroll
    for (int nt = 0; nt < 2; ++nt) {
      int n = col0 + 32 * wn + 16 * nt + lm;
#pragma unroll
      for (int r = 0; r < 4; ++r) {
        int m = row0 + 32 * wm + 16 * mt + 4 * lq + r;
        float c = acc[mt][nt][r];
        float e = 0.f;
        size_t eo = ebase + (size_t)m * N + n;
        if (E1h) {
          float t = bf2f(E1h[eo]);
          if (E1l) t += bf2f(E1l[eo]);
          e += alpha * t;
        }
        if (E2h) {
          float t = bf2f(E2h[eo]);
          if (E2l) t += bf2f(E2l[eo]);
          e += beta * t;
        }
        float y = coef * (e - c);
        ush h, l; splitf(y, h, l);
        if (oAh) {
          size_t o = ebase + (size_t)m * N + n;
          oAh[o] = h;
          if (oAl) oAl[o] = l;
        }
        if (oBh) {
          size_t o = (size_t)batch * N * M + (size_t)n * M + m;
          oBh[o] = h;
          if (oBl) oBl[o] = l;
        }
        if (oCh) oCh[ebase + (size_t)m * N + n] = f2bf(c);
      }
    }
}

__global__ __launch_bounds__(256) void bgemm_split(
    const ush* Ah, const ush* Al, const ush* Bh, const ush* Bl,
    const ush* E1h, const ush* E1l, const ush* E2h, const ush* E2l,
    ush* oAh, ush* oAl, ush* oBh, ush* oBl,
    int M, int N, int K, float alpha, float beta, float coef) {
  __shared__ ush S[2][2][8][64][8];
  stage_gemm(S, Ah, Al, Bh, Bl, E1h, E1l, E2h, E2l, oAh, oAl, oBh, oBl,
             nullptr, M, N, K, alpha, beta, coef,
             blockIdx.x, blockIdx.y, blockIdx.z, threadIdx.x);
}

// ---------------------------------------------------------------------------
// ns_s2: batched stage-2 of the 3-stage split NS iteration (iters 4-5).
// blockIdx.z parity: even -> t2 = 7Y - Y@Y; odd -> U = z@Y. r3-verified.
// ---------------------------------------------------------------------------
__global__ __launch_bounds__(256) void ns_s2(
    const ush* Yh, const ush* Yl, const ush* zh, const ush* zl,
    ush* t2h, ush* t2l, ush* Uh, ush* Ul) {
  __shared__ ush S[2][2][8][64][8];
  const int bz = blockIdx.z, batch = bz >> 1;
  if ((bz & 1) == 0) {
    stage_gemm(S, Yh, Yl, Yh, Yl, Yh, Yl, nullptr, nullptr,
               t2h, t2l, nullptr, nullptr, nullptr,
               256, 256, 256, 7.f, 0.f, 1.f,
               blockIdx.x, blockIdx.y, batch, threadIdx.x);
  } else {
    stage_gemm(S, zh, zl, Yh, Yl, nullptr, nullptr, nullptr, nullptr,
               Uh, Ul, nullptr, nullptr, nullptr,
               256, 256, 256, 0.f, 0.f, -1.f,
               blockIdx.x, blockIdx.y, batch, threadIdx.x);
  }
}

// ---------------------------------------------------------------------------
// ns_sa / ns_sb: carry-Y plain iterations (2 launches/iter, depth-minimum;
// r7-verified, absmax bit-identical, -12 us). Y carried as state:
//   Y' = a2 z' = 0.25(13Y - 15Y^2 + Y^2 t2)   [exact identity]
// ns_sa even: C=Y@Y -> t2 = 7Y - C (oA) AND Y2 = C raw (oC). odd: U = z@Y.
// ns_sb even: z' (row + B-form). odd: Y' (row; symmetric).
// Iters 4-5 recompute Y fresh (split path) -> carry drift annihilated.
// ---------------------------------------------------------------------------
__global__ __launch_bounds__(256) void ns_sa(
    const ush* Yh, const ush* zh, ush* t2h, ush* Y2h, ush* Uh) {
  __shared__ ush S[2][2][8][64][8];
  const int bz = blockIdx.z, batch = bz >> 1;
  if ((bz & 1) == 0) {
    stage_gemm(S, Yh, nullptr, Yh, nullptr, Yh, nullptr, nullptr, nullptr,
               t2h, nullptr, nullptr, nullptr, Y2h,
               256, 256, 256, 7.f, 0.f, 1.f,
               blockIdx.x, blockIdx.y, batch, threadIdx.x);
  } else {
    stage_gemm(S, zh, nullptr, Yh, nullptr, nullptr, nullptr, nullptr, nullptr,
               Uh, nullptr, nullptr, nullptr, nullptr,
               256, 256, 256, 0.f, 0.f, -1.f,
               blockIdx.x, blockIdx.y, batch, threadIdx.x);
  }
}

__global__ __launch_bounds__(256) void ns_sb(
    const ush* zh, const ush* Uh, const ush* t2h,
    const ush* Yh, const ush* Y2h,
    ush* znh, ush* znBh, ush* Ynh) {
  __shared__ ush S[2][2][8][64][8];
  const int bz = blockIdx.z, batch = bz >> 1;
  if ((bz & 1) == 0) {
    stage_gemm(S, Uh, nullptr, t2h, nullptr, zh, nullptr, Uh, nullptr,
               znh, nullptr, znBh, nullptr, nullptr,
               256, 256, 256, -13.f, 15.f, -0.25f,
               blockIdx.x, blockIdx.y, batch, threadIdx.x);
  } else {
    stage_gemm(S, Y2h, nullptr, t2h, nullptr, Yh, nullptr, Y2h, nullptr,
               Ynh, nullptr, nullptr, nullptr, nullptr,
               256, 256, 256, -13.f, 15.f, -0.25f,
               blockIdx.x, blockIdx.y, batch, threadIdx.x);
  }
}

// ---------------------------------------------------------------------------
// K6: sim3 flash via MFMA, no max-subtraction (scores tiny). n-split NCH ways.
// ---------------------------------------------------------------------------
constexpr int NCH = 4;
__global__ __launch_bounds__(256) void sim3_mfma(const float* __restrict__ qlm,
                                                 const ush* __restrict__ k_bf,
                                                 const ush* __restrict__ vT_bf,
                                                 float* __restrict__ O_part,
                                                 float* __restrict__ l_part) {
  constexpr int CHUNK = SEQ / NCH;  // 1024
  __shared__ ush Qs[64][72];
  __shared__ ush Ks[128][72];
  __shared__ ush Vs[64][136];
  __shared__ ush Ps[64][136];
  const int bh = blockIdx.z;
  const int m0 = blockIdx.x * 64;
  const int n_base = blockIdx.y * CHUNK;
  const int tid = threadIdx.x;
  const int w = tid >> 6, lane = tid & 63;
  const int lm = lane & 15, lq = lane >> 4;
  {
    int m = tid >> 2, off = (tid & 3) * 16;
    const float* src = &qlm[((size_t)bh * NLM + m0 + m) * HD + off];
    us8 o0, o1;
#pragma unroll
    for (int j = 0; j < 8; ++j) o0[j] = f2bf(src[j]);
#pragma unroll
    for (int j = 0; j < 8; ++j) o1[j] = f2bf(src[8 + j]);
    *(us8*)&Qs[m][off] = o0;
    *(us8*)&Qs[m][off + 8] = o1;
  }
  const ffrag fz = {0.f, 0.f, 0.f, 0.f};
  ffrag O[4] = {fz, fz, fz, fz};
  float lsum[4] = {0.f, 0.f, 0.f, 0.f};

  for (int n0 = 0; n0 < CHUNK; n0 += 128) {
    __syncthreads();
    {
      int n = tid >> 1, off = (tid & 1) * 32;
      const ush* src = &k_bf[((size_t)bh * SEQ + n_base + n0 + n) * HD + off];
#pragma unroll
      for (int u = 0; u < 4; ++u) *(us8*)&Ks[n][off + 8 * u] = *(const us8*)&src[8 * u];
    }
    {
      int d = tid >> 2, off = (tid & 3) * 32;
      const ush* src = &vT_bf[((size_t)bh * HD + d) * SEQ + n_base + n0 + off];
#pragma unroll
      for (int u = 0; u < 4; ++u) *(us8*)&Vs[d][off + 8 * u] = *(const us8*)&src[8 * u];
    }
    __syncthreads();
    ffrag S[8] = {fz, fz, fz, fz, fz, fz, fz, fz};
#pragma unroll
    for (int ks = 0; ks < 2; ++ks) {
      bfrag a = *(const bfrag*)&Qs[16 * w + lm][32 * ks + 8 * lq];
#pragma unroll
      for (int t = 0; t < 8; ++t) {
        bfrag b = *(const bfrag*)&Ks[16 * t + lm][32 * ks + 8 * lq];
        S[t] = __builtin_amdgcn_mfma_f32_16x16x32_bf16(a, b, S[t], 0, 0, 0);
      }
    }
#pragma unroll
    for (int t = 0; t < 8; ++t)
#pragma unroll
      for (int r = 0; r < 4; ++r) {
        float p = __expf(S[t][r]);
        lsum[r] += p;
        Ps[16 * w + 4 * lq + r][16 * t + lm] = f2bf(p);
      }
    __syncthreads();
#pragma unroll
    for (int kk = 0; kk < 4; ++kk) {
      bfrag a = *(const bfrag*)&Ps[16 * w + lm][32 * kk + 8 * lq];
#pragma unroll
      for (int t2 = 0; t2 < 4; ++t2) {
        bfrag b = *(const bfrag*)&Vs[16 * t2 + lm][32 * kk + 8 * lq];
        O[t2] = __builtin_amdgcn_mfma_f32_16x16x32_bf16(a, b, O[t2], 0, 0, 0);
      }
    }
  }
#pragma unroll
  for (int r = 0; r < 4; ++r) {
#pragma unroll
    for (int off = 1; off < 16; off <<= 1) lsum[r] += __shfl_xor(lsum[r], off);
  }
  const size_t pbase = (size_t)blockIdx.y * 32 + bh;
  if (lm == 0) {
#pragma unroll
    for (int r = 0; r < 4; ++r)
      l_part[pbase * NLM + m0 + 16 * w + 4 * lq + r] = lsum[r];
  }
#pragma unroll
  for (int t2 = 0; t2 < 4; ++t2)
#pragma unroll
    for (int r = 0; r < 4; ++r) {
      int m = m0 + 16 * w + 4 * lq + r;
      int d = 16 * t2 + lm;
      O_part[(pbase * NLM + m) * HD + d] = O[t2][r];
    }
}

// sim3_finalize: combine partials, write sv in B-form split ([d][m]).
// grid (8,32): blockIdx.x = {d-quarter (low 2 bits), m-half (bit 2)}.
__global__ __launch_bounds__(256) void sim3_finalize(const float* __restrict__ O_part,
                                                     const float* __restrict__ l_part,
                                                     ush* __restrict__ svBh,
                                                     ush* __restrict__ svBl) {
  __shared__ float T[128][17];
  __shared__ float ls[128];
  const int bh = blockIdx.y;
  const int d0 = (blockIdx.x & 3) * 16;
  const int m0 = (blockIdx.x >> 2) * 128;
  const int tid = threadIdx.x;
  if (tid < 128) {
    float s = 0.f;
#pragma unroll
    for (int c = 0; c < NCH; ++c) s += l_part[(size_t)(c * 32 + bh) * NLM + m0 + tid];
    ls[tid] = s;
  }
#pragma unroll
  for (int i = 0; i < 8; ++i) {
    int e = i * 256 + tid;          // [0, 2048)
    int m = e >> 4, dd = e & 15;
    float s = 0.f;
#pragma unroll
    for (int c = 0; c < NCH; ++c)
      s += O_part[(((size_t)(c * 32 + bh)) << 14) + (size_t)(m0 + m) * HD + d0 + dd];
    T[m][dd] = s;
  }
  __syncthreads();
#pragma unroll
  for (int i = 0; i < 8; ++i) {
    int e = i * 256 + tid;
    int dd = e >> 7, m = e & 127;
    float val = T[m][dd] / ls[m];
    ush h, l; splitf(val, h, l);
    size_t o = ((size_t)bh * HD + d0 + dd) * NLM + m0 + m;
    svBh[o] = h; svBl[o] = l;
  }
}

// ---------------------------------------------------------------------------
// K8: attn1 via MFMA: outp = softmax(q_bf @ klm^T) @ tt  (fp32 softmax)
// ---------------------------------------------------------------------------
__global__ __launch_bounds__(256) void attn1_mfma(const ush* __restrict__ q_bf,
                                                  const float* __restrict__ klm,
                                                  const ush* __restrict__ ttT,
                                                  float* __restrict__ outp) {
  __shared__ ush bufA[256 * 72];   // klm bf16 [256][72] then ttT [64][264]
  __shared__ ush bufB[64 * 264];   // qs [64][72] then Ps [64][264]
  const int bh = blockIdx.y;
  const int b = bh >> 3, h = bh & 7;
  const int i0 = blockIdx.x * 64;
  const int tid = threadIdx.x;
  const int w = tid >> 6, lane = tid & 63;
  const int lm = lane & 15, lq = lane >> 4;
  {
    int m = tid >> 2, off = (tid & 3) * 16;
    const ush* src = &q_bf[((size_t)bh * SEQ + i0 + m) * HD + off];
    *(us8*)&bufB[m * 72 + off] = *(const us8*)src;
    *(us8*)&bufB[m * 72 + off + 8] = *(const us8*)&src[8];
  }
  {
    const float* kb = klm + (size_t)bh * NLM * HD;
#pragma unroll
    for (int u = 0; u < 16; ++u) {
      int e4 = u * 256 + tid;
      float4 f = ((const float4*)kb)[e4];
      int row = e4 >> 4, col = (e4 & 15) * 4;
      ush* p = &bufA[row * 72 + col];
      p[0] = f2bf(f.x); p[1] = f2bf(f.y); p[2] = f2bf(f.z); p[3] = f2bf(f.w);
    }
  }
  __syncthreads();
  const ffrag fz = {0.f, 0.f, 0.f, 0.f};
  ffrag S[16];
#pragma unroll
  for (int t = 0; t < 16; ++t) S[t] = fz;
#pragma unroll
  for (int ks = 0; ks < 2; ++ks) {
    bfrag a = *(const bfrag*)&bufB[(16 * w + lm) * 72 + 32 * ks + 8 * lq];
#pragma unroll
    for (int t = 0; t < 16; ++t) {
      bfrag bb = *(const bfrag*)&bufA[(16 * t + lm) * 72 + 32 * ks + 8 * lq];
      S[t] = __builtin_amdgcn_mfma_f32_16x16x32_bf16(a, bb, S[t], 0, 0, 0);
    }
  }
  float rinv[4];
  float ev[16][4];
#pragma unroll
  for (int r = 0; r < 4; ++r) {
    float mx = -INFINITY;
#pragma unroll
    for (int t = 0; t < 16; ++t) mx = fmaxf(mx, S[t][r]);
#pragma unroll
    for (int off = 1; off < 16; off <<= 1) mx = fmaxf(mx, __shfl_xor(mx, off));
    float sm = 0.f;
#pragma unroll
    for (int t = 0; t < 16; ++t) { ev[t][r] = __expf(S[t][r] - mx); sm += ev[t][r]; }
#pragma unroll
    for (int off = 1; off < 16; off <<= 1) sm += __shfl_xor(sm, off);
    rinv[r] = 1.0f / sm;
  }
  __syncthreads();
#pragma unroll
  for (int t = 0; t < 16; ++t)
#pragma unroll
    for (int r = 0; r < 4; ++r)
      bufB[(16 * w + 4 * lq + r) * 264 + 16 * t + lm] = f2bf(ev[t][r]);
  {
    const ush* tb = ttT + (size_t)bh * HD * NLM;
#pragma unroll
    for (int u = 0; u < 8; ++u) {
      int e8 = u * 256 + tid;
      int row = e8 >> 5, col = (e8 & 31) * 8;
      *(us8*)&bufA[row * 264 + col] = *(const us8*)&tb[row * NLM + col];
    }
  }
  __syncthreads();
  ffrag O[4] = {fz, fz, fz, fz};
#pragma unroll
  for (int kk = 0; kk < 8; ++kk) {
    bfrag a = *(const bfrag*)&bufB[(16 * w + lm) * 264 + 32 * kk + 8 * lq];
#pragma unroll
    for (int t2 = 0; t2 < 4; ++t2) {
      bfrag bb = *(const bfrag*)&bufA[(16 * t2 + lm) * 264 + 32 * kk + 8 * lq];
      O[t2] = __builtin_amdgcn_mfma_f32_16x16x32_bf16(a, bb, O[t2], 0, 0, 0);
    }
  }
#pragma unroll
  for (int t2 = 0; t2 < 4; ++t2)
#pragma unroll
    for (int r = 0; r < 4; ++r) {
      int i = i0 + 16 * w + 4 * lq + r;
      int d = 16 * t2 + lm;
      outp[((size_t)b * SEQ + i) * DIMC + h * HD + d] = O[t2][r] * rinv[r];
    }
}

// ---------------------------------------------------------------------------
// K9: conv add + split: outp(fp32) + depthwise conv(vT) -> outph/outpl
// ---------------------------------------------------------------------------
__global__ __launch_bounds__(256) void conv_add_split(const float* __restrict__ outp,
                                                      const ush* __restrict__ vT,
                                                      const float* __restrict__ kern,
                                                      ush* __restrict__ oh,
                                                      ush* __restrict__ ol) {
  __shared__ float vt[64 * 97];   // [d][96+1], cols n0-16 .. n0+79
  __shared__ float ks[KWIN];
  const int bh = blockIdx.y;
  const int b = bh >> 3, hh = bh & 7;
  const int n0 = blockIdx.x * 64;
  const int tid = threadIdx.x;
  if (tid < KWIN) ks[tid] = kern[hh * KWIN + tid];
  for (int e = tid; e < 64 * 96; e += 256) {
    int d = e / 96, c = e % 96;
    int n = n0 - 16 + c;
    vt[d * 97 + c] = (n >= 0 && n < SEQ) ? bf2f(vT[((size_t)bh * HD + d) * SEQ + n]) : 0.f;
  }
  __syncthreads();
  const int d = tid & 63, g = tid >> 6;
  float wreg[48];
#pragma unroll
  for (int j = 0; j < 48; ++j) wreg[j] = vt[d * 97 + g * 16 + j];
#pragma unroll
  for (int nn = 0; nn < 16; ++nn) {
    float s = 0.f;
#pragma unroll
    for (int t = 0; t < KWIN; ++t) s = fmaf(ks[t], wreg[nn + t], s);
    int n = n0 + g * 16 + nn;
    size_t o = ((size_t)b * SEQ + n) * DIMC + hh * HD + d;
    float val = outp[o] + s;
    ush h, l; splitf(val, h, l);
    oh[o] = h; ol[o] = l;
  }
}

// ---------------------------------------------------------------------------
// K10: out = outp_split @ WoutT_split + bias (3-product: final projection is
// precision-critical, keep full split). BM=BN=128, grid (128, 4)
// ---------------------------------------------------------------------------
__global__ __launch_bounds__(256) void out_gemm_split(const ush* __restrict__ ah_g,
                                                      const ush* __restrict__ al_g,
                                                      const ush* __restrict__ bh_g,
                                                      const ush* __restrict__ bl_g,
                                                      const float* __restrict__ bias,
                                                      float* __restrict__ out) {
  __shared__ ush Ash[128][40], Asl[128][40];
  __shared__ ush Bsh[128][40], Bsl[128][40];
  const int tid = threadIdx.x;
  const int w = tid >> 6, lane = tid & 63;
  const int lm = lane & 15, lq = lane >> 4;
  const int wm = w >> 1, wn = w & 1;
  const int row0 = blockIdx.x * 128, col0 = blockIdx.y * 128;
  const ffrag fz = {0.f, 0.f, 0.f, 0.f};
  ffrag acc[4][4];
#pragma unroll
  for (int i = 0; i < 4; ++i)
#pragma unroll
    for (int j = 0; j < 4; ++j) acc[i][j] = fz;

  const int sm = tid >> 1, skoff = (tid & 1) * 16;
  for (int k0 = 0; k0 < 512; k0 += 32) {
    __syncthreads();
    {
      size_t ao = (size_t)(row0 + sm) * 512 + k0 + skoff;
      *(us8*)&Ash[sm][skoff]     = *(const us8*)&ah_g[ao];
      *(us8*)&Ash[sm][skoff + 8] = *(const us8*)&ah_g[ao + 8];
      *(us8*)&Asl[sm][skoff]     = *(const us8*)&al_g[ao];
      *(us8*)&Asl[sm][skoff + 8] = *(const us8*)&al_g[ao + 8];
      size_t bo = (size_t)(col0 + sm) * 512 + k0 + skoff;
      *(us8*)&Bsh[sm][skoff]     = *(const us8*)&bh_g[bo];
      *(us8*)&Bsh[sm][skoff + 8] = *(const us8*)&bh_g[bo + 8];
      *(us8*)&Bsl[sm][skoff]     = *(const us8*)&bl_g[bo];
      *(us8*)&Bsl[sm][skoff + 8] = *(const us8*)&bl_g[bo + 8];
    }
    __syncthreads();
    bfrag ah[4], al[4], bh[4], bl[4];
#pragma unroll
    for (int mt = 0; mt < 4; ++mt) {
      ah[mt] = *(const bfrag*)&Ash[64 * wm + 16 * mt + lm][8 * lq];
      al[mt] = *(const bfrag*)&Asl[64 * wm + 16 * mt + lm][8 * lq];
    }
#pragma unroll
    for (int nt = 0; nt < 4; ++nt) {
      bh[nt] = *(const bfrag*)&Bsh[64 * wn + 16 * nt + lm][8 * lq];
      bl[nt] = *(const bfrag*)&Bsl[64 * wn + 16 * nt + lm][8 * lq];
    }
#pragma unroll
    for (int mt = 0; mt < 4; ++mt)
#pragma unroll
      for (int nt = 0; nt < 4; ++nt) {
        acc[mt][nt] = __builtin_amdgcn_mfma_f32_16x16x32_bf16(ah[mt], bh[nt], acc[mt][nt], 0, 0, 0);
        acc[mt][nt] = __builtin_amdgcn_mfma_f32_16x16x32_bf16(al[mt], bh[nt], acc[mt][nt], 0, 0, 0);
        acc[mt][nt] = __builtin_amdgcn_mfma_f32_16x16x32_bf16(ah[mt], bl[nt], acc[mt][nt], 0, 0, 0);
      }
  }
#pragma unroll
  for (int mt = 0; mt < 4; ++mt)
#pragma unroll
    for (int nt = 0; nt < 4; ++nt) {
      int n = col0 + 64 * wn + 16 * nt + lm;
      float bv = bias[n];
#pragma unroll
      for (int r = 0; r < 4; ++r) {
        int m = row0 + 64 * wm + 16 * mt + 4 * lq + r;
        out[(size_t)m * 512 + n] = acc[mt][nt][r] + bv;
      }
    }
}

// ---------------------------------------------------------------------------
extern "C" void kernel_launch(void* const* d_in, const int* in_sizes, int n_in,
                              void* d_out, int out_size, void* d_ws, size_t ws_size,
                              hipStream_t stream) {
  const float* x    = (const float*)d_in[0];
  const float* Wqkv = (const float*)d_in[1];
  const float* Wout = (const float*)d_in[2];
  const float* bout = (const float*)d_in[3];
  const float* rker = (const float*)d_in[4];
  float* out = (float*)d_out;
  float* ws = (float*)d_ws;

  // workspace layout (float-element offsets), total ~186.6 MB
  ush*   vT     = (ush*)(ws);                          // 8388608 ush (v transposed)
  ush*   q_bf   = (ush*)(ws + 4194304);                // 8388608 ush
  float* regA   = ws + 8388608;                        // 8388608 f: k_bf -> outp
  float* regB   = ws + 16777216;                       // 8388608 f: xh+xl -> outph+outpl
  float* qlm    = ws + 25165824;                       // 524288
  float* klm    = ws + 25690112;                       // 524288
  float* regC   = ws + 26214400;                       // 2097152 f: t2(h,l) / ttT
  float* a2reg  = ws + 28311552;                       // 2097152 f: a2h+a2l
  float* zAreg  = ws + 30408704;                       // 4194304 f
  float* zBreg  = ws + 34603008;                       // 4194304 f
  float* xzreg  = ws + 38797312;                       // 4194304 f: Y ping-pong (later O_part/l_part)
  float* t3reg  = ws + 43515904;                       // 2097152 f: U + Y2 (later svB)
  float* wqkvT  = ws + 45613056;                       // 786432 f
  float* woutT  = ws + 46399488;                       // 262144 f
  float* red    = ws + 46661632;                       // 128

  ush* k_bf  = (ush*)regA;
  float* outp = regA;
  ush* xh = (ush*)regB;                 // 8388608 ush
  ush* xl = (ush*)(regB + 4194304);     // 8388608 ush
  ush* outph = (ush*)regB;
  ush* outpl = (ush*)(regB + 4194304);
  ush* a2h = (ush*)a2reg;               // 2097152 ush each
  ush* a2l = (ush*)(a2reg + 1048576);
  ush* zA_[4] = {(ush*)zAreg, (ush*)(zAreg + 1048576), (ush*)(zAreg + 2097152), (ush*)(zAreg + 3145728)};
  ush* zB_[4] = {(ush*)zBreg, (ush*)(zBreg + 1048576), (ush*)(zBreg + 2097152), (ush*)(zBreg + 3145728)};
  ush* Y_h  = (ush*)xzreg;              // Y ping-pong (hi); lo slot doubles as ping B
  ush* Y_l  = (ush*)(xzreg + 1048576);  //   during plain carry-Y iters (lo dead)
  ush* t2_h = (ush*)regC;               // t2 = 7Y - Y^2, symmetric (row-major)
  ush* t2_l = (ush*)(regC + 1048576);
  ush* U_h  = (ush*)t3reg;              // U = z@Y (row-major)
  ush* U_l  = (ush*)(t3reg + 1048576);  // split iters: U lo; plain iters: Y2
  ush* Y2_h = U_l;                      // Y^2 (raw C tap) during plain iters
  float* O_part = xzreg;                // after pinv
  float* l_part = xzreg + 2097152;
  ush* svB_h = (ush*)t3reg;             // after pinv
  ush* svB_l = (ush*)(t3reg + 262144);
  ush* ttT   = (ush*)regC;              // after pinv
  ush* wqkvT_h = (ush*)wqkvT;
  ush* wqkvT_l = (ush*)(wqkvT + 393216);
  ush* woutT_h = (ush*)woutT;
  ush* woutT_l = (ush*)(woutT + 131072);

  // --- pre-splits ---
  split_flat<<<2048, 256, 0, stream>>>(x, xh, xl, 2097152);
  transpose_split_w<<<dim3(48, 16), 256, 0, stream>>>(Wqkv, wqkvT_h, wqkvT_l, 512, 1536);
  transpose_split_w<<<dim3(16, 16), 256, 0, stream>>>(Wout, woutT_h, woutT_l, 512, 512);

  // --- qkv + landmarks (+ direct vT) ---
  qkv_mfma<<<dim3(128, 12), 256, 0, stream>>>(xh, xl, wqkvT_h,
                                              q_bf, k_bf, vT, qlm, klm);

  // --- attn2 + pinv init ---
  sim2_softmax<<<8192, 256, 0, stream>>>(qlm, klm, a2h, a2l);
  colmax<<<32, 256, 0, stream>>>(a2h, red);
  finalize_scale<<<1, 64, 0, stream>>>(red);
  zinit_split<<<dim3(8, 8, 32), 256, 0, stream>>>(a2h, a2l, red,
                                                  zA_[0], zA_[1], zA_[2], zA_[3]);

  // --- pinv Newton-Schulz (launch-synchronized; r4/r5: never re-fuse) ---
  // Plain iters 0-3: carry-Y, 2 launches/iter (depth-minimum, r7-verified).
  // Iters 4-5: proven 3-stage split path, Y recomputed fresh from a2@z.
  ush** zc = zA_;
  ush** zn = zB_;
  ush* Yc = Y_h;
  ush* Yn = Y_l;   // lo slot dead during plain iters -> Y ping B
  // Y0 = a2 @ z0 (plain)
  bgemm_split<<<dim3(4, 4, 32), 256, 0, stream>>>(
      a2h, nullptr, zc[2], nullptr,
      nullptr, nullptr, nullptr, nullptr,
      Yc, nullptr, nullptr, nullptr,
      256, 256, 256, 0.f, 0.f, -1.f);
  for (int it = 0; it < 4; ++it) {
    ns_sa<<<dim3(4, 4, 64), 256, 0, stream>>>(Yc, zc[0], t2_h, Y2_h, U_h);
    ns_sb<<<dim3(4, 4, 64), 256, 0, stream>>>(zc[0], U_h, t2_h, Yc, Y2_h,
                                              zn[0], zn[2], Yn);
    ush** tp = zc; zc = zn; zn = tp;
    ush* ty = Yc; Yc = Yn; Yn = ty;
  }
  for (int it = 4; it < 6; ++it) {
    const bool zin_s = (it == 5);
    // S1: Y = a2 @ z (full split, fresh consistency)
    bgemm_split<<<dim3(4, 4, 32), 256, 0, stream>>>(
        a2h, a2l, zc[2], zin_s ? zc[3] : nullptr,
        nullptr, nullptr, nullptr, nullptr,
        Y_h, Y_l, nullptr, nullptr,
        256, 256, 256, 0.f, 0.f, -1.f);
    // S2: t2 = 7Y - Y@Y ; U = z@Y
    ns_s2<<<dim3(4, 4, 64), 256, 0, stream>>>(
        Y_h, Y_l, zc[0], zin_s ? zc[1] : nullptr,
        t2_h, t2_l, U_h, U_l);
    // S3: z' = 0.25*(13 z - 15 U + U@t2)
    bgemm_split<<<dim3(4, 4, 32), 256, 0, stream>>>(
        U_h, U_l, t2_h, t2_l,
        zc[0], zin_s ? zc[1] : nullptr,
        U_h, U_l,
        zn[0], zn[1], zn[2], zn[3],
        256, 256, 256, -13.f, 15.f, -0.25f);
    ush** tp = zc; zc = zn; zn = tp;
  }
  // after 6 swaps zc == zA_ (attn2_inv, full split)

  // --- sim3 (flash) ---
  sim3_mfma<<<dim3(4, NCH, 32), 256, 0, stream>>>(qlm, k_bf, vT, O_part, l_part);
  sim3_finalize<<<dim3(8, 32), 256, 0, stream>>>(O_part, l_part, svB_h, svB_l);

  // --- tt = attn2_inv @ sv (write ttT = tt^T plain bf16) ---
  bgemm_split<<<dim3(4, 1, 32), 256, 0, stream>>>(
      zc[0], zc[1], svB_h, svB_l,
      nullptr, nullptr, nullptr, nullptr,
      nullptr, nullptr, ttT, nullptr, 256, 64, 256, 0.f, 0.f, -1.f);

  // --- attn1 + conv + output projection ---
  attn1_mfma<<<dim3(64, 32), 256, 0, stream>>>(q_bf, klm, ttT, outp);
  conv_add_split<<<dim3(64, 32), 256, 0, stream>>>(outp, vT, rker, outph, outpl);
  out_gemm_split<<<dim3(128, 4), 256, 0, stream>>>(outph, outpl, woutT_h, woutT_l, bout, out);
}

// Round 9
// 701.092 us; speedup vs baseline: 1.0932x; 1.0932x over previous
//
#include <hip/hip_runtime.h>
#include <math.h>

// Problem constants
constexpr int BATCH = 4;
constexpr int SEQ   = 4096;
constexpr int DIMC  = 512;
constexpr int NH    = 8;
constexpr int HD    = 64;
constexpr int NLM   = 256;   // landmarks M
constexpr int LWIN  = 16;    // SEQ / NLM
constexpr int KWIN  = 33;
constexpr int BH    = BATCH * NH; // 32

typedef __attribute__((ext_vector_type(8))) short  bfrag;  // 8 bf16 for MFMA A/B
typedef __attribute__((ext_vector_type(4))) float  ffrag;  // MFMA C/D
typedef __attribute__((ext_vector_type(8))) unsigned short us8;
typedef __attribute__((ext_vector_type(4))) unsigned short us4;
typedef unsigned short ush;

__device__ __forceinline__ ush f2bf(float f) {
  unsigned u = __builtin_bit_cast(unsigned, f);
  return (ush)((u + 0x7FFFu + ((u >> 16) & 1u)) >> 16);
}
__device__ __forceinline__ float bf2f(ush h) {
  unsigned u = ((unsigned)h) << 16;
  return __builtin_bit_cast(float, u);
}
__device__ __forceinline__ void splitf(float f, ush& h, ush& l) {
  h = f2bf(f);
  l = f2bf(f - bf2f(h));
}
// async global->LDS, 16B per lane: LDS dest = base + lane*16 (wave-uniform base)
__device__ __forceinline__ void gl_lds16(const ush* g, ush* l) {
  __builtin_amdgcn_global_load_lds(
      (const __attribute__((address_space(1))) void*)g,
      (__attribute__((address_space(3))) void*)l, 16, 0, 0);
}

// ---------------------------------------------------------------------------
// split_flat: fp32 -> (hi, lo) bf16, elementwise (x pre-split). Grid-stride.
// ---------------------------------------------------------------------------
__global__ void split_flat(const float* __restrict__ src, ush* __restrict__ oh,
                           ush* __restrict__ ol, int n4) {
  for (int i = blockIdx.x * 256 + threadIdx.x; i < n4; i += gridDim.x * 256) {
    float4 f = ((const float4*)src)[i];
    us4 h, l;
    float fs[4] = {f.x, f.y, f.z, f.w};
#pragma unroll
    for (int j = 0; j < 4; ++j) {
      ush hh, ll;
      splitf(fs[j], hh, ll);
      h[j] = hh; l[j] = ll;
    }
    ((us4*)oh)[i] = h;
    ((us4*)ol)[i] = l;
  }
}

// ---------------------------------------------------------------------------
// transpose_split_w: in [R][C] fp32 -> out [C][R] hi/lo bf16 (weights)
// ---------------------------------------------------------------------------
__global__ __launch_bounds__(256) void transpose_split_w(const float* __restrict__ in,
                                                         ush* __restrict__ oh,
                                                         ush* __restrict__ ol,
                                                         int R, int C) {
  __shared__ float T[32][33];
  const int tid = threadIdx.x;
  const int c0 = blockIdx.x * 32, r0 = blockIdx.y * 32;
#pragma unroll
  for (int u = 0; u < 4; ++u) {
    int r = (tid >> 5) * 4 + u, cl = tid & 31;
    T[r][cl] = in[(size_t)(r0 + r) * C + c0 + cl];
  }
  __syncthreads();
#pragma unroll
  for (int u = 0; u < 4; ++u) {
    int cl = (tid >> 5) * 4 + u, rl = tid & 31;
    float f = T[rl][cl];
    ush h, l; splitf(f, h, l);
    size_t o = (size_t)(c0 + cl) * R + r0 + rl;
    oh[o] = h; ol[o] = l;
  }
}

// ---------------------------------------------------------------------------
// K1: qkv MFMA GEMM — ROUND-9: r6's us8 VGPR staging (proven 83.5us
// throughput: ~1536 independent loads in flight, compiler-pipelined) writing
// into r7's fragment-major LDS layout [plane][chunk][128][8] (proven
// 0-conflict on both store and ds_read sides). r7/r8 closed the DMA path:
// global_load_lds caps queue depth at wave-issue count -> latency-bound
// (136/144us). BK=32, LDS 24KB. 2-product split (x split, W hi-only).
// Epilogue: q/k bf16 + landmark pooling; v written DIRECTLY TRANSPOSED.
// ---------------------------------------------------------------------------
__global__ __launch_bounds__(256) void qkv_mfma(const ush* __restrict__ xh,
                                                const ush* __restrict__ xl,
                                                const ush* __restrict__ wTh,
                                                ush* __restrict__ q_bf,
                                                ush* __restrict__ k_bf,
                                                ush* __restrict__ vT,
                                                float* __restrict__ qlm,
                                                float* __restrict__ klm) {
  __shared__ ush S[3][4][128][8];   // 24 KB fragment-major: {xh, xl, wTh}
  const int tid = threadIdx.x;
  const int w = tid >> 6, lane = tid & 63;
  const int lm = lane & 15, lq = lane >> 4;
  const int wm = w >> 1, wn = w & 1;
  const int row0 = blockIdx.x * 128, col0 = blockIdx.y * 128;
  const ffrag fz = {0.f, 0.f, 0.f, 0.f};
  ffrag acc[4][4];
#pragma unroll
  for (int i = 0; i < 4; ++i)
#pragma unroll
    for (int j = 0; j < 4; ++j) acc[i][j] = fz;

  const int sm = tid >> 1, hf = tid & 1;   // row 0..127, k-half 0..1
  for (int k0 = 0; k0 < 512; k0 += 32) {
    __syncthreads();
    {
      size_t ao = (size_t)(row0 + sm) * 512 + k0 + 16 * hf;
      us8 a0 = *(const us8*)&xh[ao];
      us8 a1 = *(const us8*)&xh[ao + 8];
      us8 l0 = *(const us8*)&xl[ao];
      us8 l1 = *(const us8*)&xl[ao + 8];
      size_t bo = (size_t)(col0 + sm) * 512 + k0 + 16 * hf;
      us8 b0 = *(const us8*)&wTh[bo];
      us8 b1 = *(const us8*)&wTh[bo + 8];
      // fragment-major stores: consecutive lanes -> consecutive rows ->
      // uniform bank spread (measured 0 conflicts in r7/r8)
      *(us8*)&S[0][2 * hf][sm][0]     = a0;
      *(us8*)&S[0][2 * hf + 1][sm][0] = a1;
      *(us8*)&S[1][2 * hf][sm][0]     = l0;
      *(us8*)&S[1][2 * hf + 1][sm][0] = l1;
      *(us8*)&S[2][2 * hf][sm][0]     = b0;
      *(us8*)&S[2][2 * hf + 1][sm][0] = b1;
    }
    __syncthreads();
    bfrag ah[4], al[4], bh[4];
#pragma unroll
    for (int mt = 0; mt < 4; ++mt) {
      ah[mt] = *(const bfrag*)&S[0][lq][64 * wm + 16 * mt + lm][0];
      al[mt] = *(const bfrag*)&S[1][lq][64 * wm + 16 * mt + lm][0];
    }
#pragma unroll
    for (int nt = 0; nt < 4; ++nt)
      bh[nt] = *(const bfrag*)&S[2][lq][64 * wn + 16 * nt + lm][0];
#pragma unroll
    for (int mt = 0; mt < 4; ++mt)
#pragma unroll
      for (int nt = 0; nt < 4; ++nt) {
        acc[mt][nt] = __builtin_amdgcn_mfma_f32_16x16x32_bf16(ah[mt], bh[nt], acc[mt][nt], 0, 0, 0);
        acc[mt][nt] = __builtin_amdgcn_mfma_f32_16x16x32_bf16(al[mt], bh[nt], acc[mt][nt], 0, 0, 0);
      }
  }
  // epilogue (unchanged, r4-r8 verified)
#pragma unroll
  for (int mt = 0; mt < 4; ++mt) {
    int rbase = row0 + 64 * wm + 16 * mt;      // 16-aligned -> single window
    int b = rbase >> 12;
    int ntok_base = rbase & 4095;
    int win = ntok_base >> 4;
#pragma unroll
    for (int nt = 0; nt < 4; ++nt) {
      int n_local = 64 * wn + 16 * nt;          // frag col base (h uniform)
      int col = col0 + n_local + lm;
      int which = col >> 9;                     // 0=q 1=k 2=v
      int h = (col >> 6) & 7;
      int d = col & 63;
      int bh_i = b * NH + h;
      float scale = (which == 0) ? 0.125f : 1.0f;
      float vals[4];
      float s = 0.f;
#pragma unroll
      for (int r = 0; r < 4; ++r) {
        vals[r] = acc[mt][nt][r] * scale;
        s += vals[r];
      }
      if (which == 2) {
        ush* dst = &vT[((size_t)bh_i * HD + d) * SEQ + ntok_base + 4 * lq];
#pragma unroll
        for (int r = 0; r < 4; ++r) dst[r] = f2bf(vals[r]);
      } else {
        ush* dst = which == 0 ? q_bf : k_bf;
#pragma unroll
        for (int r = 0; r < 4; ++r) {
          int ntok = ntok_base + 4 * lq + r;
          dst[((size_t)bh_i * SEQ + ntok) * HD + d] = f2bf(vals[r]);
        }
        s += __shfl_xor(s, 16);
        s += __shfl_xor(s, 32);
        if (lq == 0) {
          float* lmdst = which == 0 ? qlm : klm;
          lmdst[((size_t)bh_i * NLM + win) * HD + d] = s * (1.0f / LWIN);
        }
      }
    }
  }
}

// ---------------------------------------------------------------------------
// K3: attn2 = softmax(qlm @ klm^T) rows -> split bf16 (a2h/a2l)
// ---------------------------------------------------------------------------
__global__ __launch_bounds__(256) void sim2_softmax(const float* __restrict__ qlm,
                                                    const float* __restrict__ klm,
                                                    ush* __restrict__ a2h,
                                                    ush* __restrict__ a2l) {
  int i = blockIdx.x & 255;
  int bh = blockIdx.x >> 8;
  int j = threadIdx.x;
  __shared__ float qrow[64];
  __shared__ float red[256];
  if (j < 64) qrow[j] = qlm[((size_t)bh * NLM + i) * HD + j];
  __syncthreads();
  const float* kr = klm + ((size_t)bh * NLM + j) * HD;
  float s = 0.f;
#pragma unroll
  for (int d = 0; d < 64; d += 4) {
    float4 kv = *(const float4*)&kr[d];
    s += qrow[d] * kv.x + qrow[d + 1] * kv.y + qrow[d + 2] * kv.z + qrow[d + 3] * kv.w;
  }
  red[j] = s; __syncthreads();
  for (int off = 128; off > 0; off >>= 1) {
    if (j < off) red[j] = fmaxf(red[j], red[j + off]);
    __syncthreads();
  }
  float mx = red[0]; __syncthreads();
  float e = expf(s - mx);
  red[j] = e; __syncthreads();
  for (int off = 128; off > 0; off >>= 1) {
    if (j < off) red[j] += red[j + off];
    __syncthreads();
  }
  float val = e / red[0];
  size_t o = ((size_t)bh * NLM + i) * NLM + j;
  ush h, l; splitf(val, h, l);
  a2h[o] = h; a2l[o] = l;
}

// ---------------------------------------------------------------------------
// K4a: per-bh column sums of attn2 (hi plane only), block max.
// attn2 rows are softmax rows -> row sums are exactly 1.
// ---------------------------------------------------------------------------
__global__ __launch_bounds__(256) void colmax(const ush* __restrict__ a2h,
                                              float* __restrict__ red) {
  int bh = blockIdx.x;
  int t = threadIdx.x;
  const size_t base = (size_t)bh * NLM * NLM;
  float cs = 0.f;
  for (int i = 0; i < NLM; ++i) cs += bf2f(a2h[base + (size_t)i * NLM + t]);
  __shared__ float r1[256];
  r1[t] = cs; __syncthreads();
  for (int off = 128; off > 0; off >>= 1) {
    if (t < off) r1[t] = fmaxf(r1[t], r1[t + off]);
    __syncthreads();
  }
  if (t == 0) red[bh] = r1[0];
}

__global__ void finalize_scale(float* __restrict__ red) {
  if (threadIdx.x == 0) {
    float m1 = -1e30f;
    for (int i = 0; i < BH; ++i) m1 = fmaxf(m1, red[i]);
    red[64] = 1.0f / m1;   // row-sum max == 1 exactly (softmax rows)
  }
}

// ---------------------------------------------------------------------------
// K4c: z0 = attn2^T * invscale, A-form + B-form splits
// ---------------------------------------------------------------------------
__global__ __launch_bounds__(256) void zinit_split(const ush* __restrict__ a2h,
                                                   const ush* __restrict__ a2l,
                                                   const float* __restrict__ red,
                                                   ush* __restrict__ zAh, ush* __restrict__ zAl,
                                                   ush* __restrict__ zBh, ush* __restrict__ zBl) {
  __shared__ float T[32][33];
  const int tid = threadIdx.x;
  const int bh = blockIdx.z;
  const int j0 = blockIdx.x * 32, i0 = blockIdx.y * 32;
  const float s = red[64];
  const size_t base = (size_t)bh * NLM * NLM;
#pragma unroll
  for (int u = 0; u < 4; ++u) {
    int jl = (tid >> 5) * 4 + u, il = tid & 31;
    size_t o = base + (size_t)(j0 + jl) * NLM + i0 + il;
    float a = (bf2f(a2h[o]) + bf2f(a2l[o])) * s;
    T[jl][il] = a;
    ush h, l; splitf(a, h, l);
    zBh[o] = h; zBl[o] = l;   // zB[j][i] = a2[j][i]*s
  }
  __syncthreads();
#pragma unroll
  for (int u = 0; u < 4; ++u) {
    int il = (tid >> 5) * 4 + u, jl = tid & 31;
    float a = T[jl][il];
    ush h, l; splitf(a, h, l);
    size_t o = base + (size_t)(i0 + il) * NLM + j0 + jl;  // zA[i][j] = a2[j][i]*s
    zAh[o] = h; zAl[o] = l;
  }
}

// ---------------------------------------------------------------------------
// K5 core: one 64x64 tile of C = A@B^T(stored) with split-bf16 planes.
// m97 structure: global_load_lds staging, BK=64. Null lo-pointers skip planes.
// Epilogue: y = coef * (alpha*E1 + beta*E2 - C); outputs row-major (oA),
// transposed B-form (oB), and optional RAW C (oC, hi bf16 row-major — the
// carry-Y tap). FORCEINLINE ONLY (noinline corrupted global_load_lds -> r2).
// NOTE (r4/r5): in-kernel barrier fusion is structurally HBM-bound — never
// re-fuse.
// ---------------------------------------------------------------------------
__device__ __forceinline__ void stage_gemm(
    ush (*S)[2][8][64][8],   // LDS [2][2][8][64][8] = 32 KB
    const ush* Ah, const ush* Al, const ush* Bh, const ush* Bl,
    const ush* E1h, const ush* E1l, const ush* E2h, const ush* E2l,
    ush* oAh, ush* oAl, ush* oBh, ush* oBl, ush* oCh,
    int M, int N, int K, float alpha, float beta, float coef,
    int bx, int by, int batch, int tid) {
  const size_t abase = (size_t)batch * M * K;
  const size_t bbase = (size_t)batch * N * K;
  const size_t ebase = (size_t)batch * M * N;
  const int w = tid >> 6, lane = tid & 63;
  const int lm = lane & 15, lq = lane >> 4;
  const int wm = w >> 1, wn = w & 1;
  const int row0 = bx * 64, col0 = by * 64;
  const bool uAl = (Al != nullptr);
  const bool uBl = (Bl != nullptr);
  const ffrag fz = {0.f, 0.f, 0.f, 0.f};
  ffrag acc[2][2] = {{fz, fz}, {fz, fz}};

  const size_t arow = abase + (size_t)(row0 + lane) * K;   // per-lane
  const size_t brow = bbase + (size_t)(col0 + lane) * K;

  for (int k0 = 0; k0 < K; k0 += 64) {
    __syncthreads();
    // wave w stages k-chunks {2w, 2w+1} for A and B (lo planes only if used)
#pragma unroll
    for (int ci = 0; ci < 2; ++ci) {
      int c = 2 * w + ci;
      gl_lds16(&Ah[arow + k0 + 8 * c], &S[0][0][c][0][0]);
      gl_lds16(&Bh[brow + k0 + 8 * c], &S[1][0][c][0][0]);
      if (uAl) gl_lds16(&Al[arow + k0 + 8 * c], &S[0][1][c][0][0]);
      if (uBl) gl_lds16(&Bl[brow + k0 + 8 * c], &S[1][1][c][0][0]);
    }
    __syncthreads();   // compiler emits vmcnt(0) drain here (m97 structure)
#pragma unroll
    for (int ks = 0; ks < 2; ++ks) {
      bfrag ah[2], al[2], bhf[2], blf[2];
#pragma unroll
      for (int mt = 0; mt < 2; ++mt) {
        ah[mt] = *(const bfrag*)&S[0][0][4 * ks + lq][32 * wm + 16 * mt + lm][0];
        if (uAl) al[mt] = *(const bfrag*)&S[0][1][4 * ks + lq][32 * wm + 16 * mt + lm][0];
      }
#pragma unroll
      for (int nt = 0; nt < 2; ++nt) {
        bhf[nt] = *(const bfrag*)&S[1][0][4 * ks + lq][32 * wn + 16 * nt + lm][0];
        if (uBl) blf[nt] = *(const bfrag*)&S[1][1][4 * ks + lq][32 * wn + 16 * nt + lm][0];
      }
#pragma unroll
      for (int mt = 0; mt < 2; ++mt)
#pragma unroll
        for (int nt = 0; nt < 2; ++nt) {
          acc[mt][nt] = __builtin_amdgcn_mfma_f32_16x16x32_bf16(ah[mt], bhf[nt], acc[mt][nt], 0, 0, 0);
          if (uAl) acc[mt][nt] = __builtin_amdgcn_mfma_f32_16x16x32_bf16(al[mt], bhf[nt], acc[mt][nt], 0, 0, 0);
          if (uBl) acc[mt][nt] = __builtin_amdgcn_mfma_f32_16x16x32_bf16(ah[mt], blf[nt], acc[mt][nt], 0, 0, 0);
        }
    }
  }
#pragma unroll
  for (int mt = 0; mt < 2; ++mt)
#pragma unroll
    for (int nt = 0; nt < 2; ++nt) {
      int n = col0 + 32 * wn + 16 * nt + lm;
#pragma unroll
      for (int r = 0; r < 4; ++r) {
        int m = row0 + 32 * wm + 16 * mt + 4 * lq + r;
        float c = acc[mt][nt][r];
        float e = 0.f;
        size_t eo = ebase + (size_t)m * N + n;
        if (E1h) {
          float t = bf2f(E1h[eo]);
          if (E1l) t += bf2f(E1l[eo]);
          e += alpha * t;
        }
        if (E2h) {
          float t = bf2f(E2h[eo]);
          if (E2l) t += bf2f(E2l[eo]);
          e += beta * t;
        }
        float y = coef * (e - c);
        ush h, l; splitf(y, h, l);
        if (oAh) {
          size_t o = ebase + (size_t)m * N + n;
          oAh[o] = h;
          if (oAl) oAl[o] = l;
        }
        if (oBh) {
          size_t o = (size_t)batch * N * M + (size_t)n * M + m;
          oBh[o] = h;
          if (oBl) oBl[o] = l;
        }
        if (oCh) oCh[ebase + (size_t)m * N + n] = f2bf(c);
      }
    }
}

__global__ __launch_bounds__(256) void bgemm_split(
    const ush* Ah, const ush* Al, const ush* Bh, const ush* Bl,
    const ush* E1h, const ush* E1l, const ush* E2h, const ush* E2l,
    ush* oAh, ush* oAl, ush* oBh, ush* oBl,
    int M, int N, int K, float alpha, float beta, float coef) {
  __shared__ ush S[2][2][8][64][8];
  stage_gemm(S, Ah, Al, Bh, Bl, E1h, E1l, E2h, E2l, oAh, oAl, oBh, oBl,
             nullptr, M, N, K, alpha, beta, coef,
             blockIdx.x, blockIdx.y, blockIdx.z, threadIdx.x);
}

// ---------------------------------------------------------------------------
// ns_s2: batched stage-2 of the 3-stage split NS iteration (iters 4-5).
// blockIdx.z parity: even -> t2 = 7Y - Y@Y; odd -> U = z@Y. r3-verified.
// ---------------------------------------------------------------------------
__global__ __launch_bounds__(256) void ns_s2(
    const ush* Yh, const ush* Yl, const ush* zh, const ush* zl,
    ush* t2h, ush* t2l, ush* Uh, ush* Ul) {
  __shared__ ush S[2][2][8][64][8];
  const int bz = blockIdx.z, batch = bz >> 1;
  if ((bz & 1) == 0) {
    stage_gemm(S, Yh, Yl, Yh, Yl, Yh, Yl, nullptr, nullptr,
               t2h, t2l, nullptr, nullptr, nullptr,
               256, 256, 256, 7.f, 0.f, 1.f,
               blockIdx.x, blockIdx.y, batch, threadIdx.x);
  } else {
    stage_gemm(S, zh, zl, Yh, Yl, nullptr, nullptr, nullptr, nullptr,
               Uh, Ul, nullptr, nullptr, nullptr,
               256, 256, 256, 0.f, 0.f, -1.f,
               blockIdx.x, blockIdx.y, batch, threadIdx.x);
  }
}

// ---------------------------------------------------------------------------
// ns_sa / ns_sb: carry-Y plain iterations (2 launches/iter, depth-minimum;
// r7/r8-verified, absmax bit-identical). Y carried as state:
//   Y' = a2 z' = 0.25(13Y - 15Y^2 + Y^2 t2)   [exact identity]
// ns_sa even: C=Y@Y -> t2 = 7Y - C (oA) AND Y2 = C raw (oC). odd: U = z@Y.
// ns_sb even: z' (row + B-form). odd: Y' (row; symmetric).
// Iters 4-5 recompute Y fresh (split path) -> carry drift annihilated.
// ---------------------------------------------------------------------------
__global__ __launch_bounds__(256) void ns_sa(
    const ush* Yh, const ush* zh, ush* t2h, ush* Y2h, ush* Uh) {
  __shared__ ush S[2][2][8][64][8];
  const int bz = blockIdx.z, batch = bz >> 1;
  if ((bz & 1) == 0) {
    stage_gemm(S, Yh, nullptr, Yh, nullptr, Yh, nullptr, nullptr, nullptr,
               t2h, nullptr, nullptr, nullptr, Y2h,
               256, 256, 256, 7.f, 0.f, 1.f,
               blockIdx.x, blockIdx.y, batch, threadIdx.x);
  } else {
    stage_gemm(S, zh, nullptr, Yh, nullptr, nullptr, nullptr, nullptr, nullptr,
               Uh, nullptr, nullptr, nullptr, nullptr,
               256, 256, 256, 0.f, 0.f, -1.f,
               blockIdx.x, blockIdx.y, batch, threadIdx.x);
  }
}

__global__ __launch_bounds__(256) void ns_sb(
    const ush* zh, const ush* Uh, const ush* t2h,
    const ush* Yh, const ush* Y2h,
    ush* znh, ush* znBh, ush* Ynh) {
  __shared__ ush S[2][2][8][64][8];
  const int bz = blockIdx.z, batch = bz >> 1;
  if ((bz & 1) == 0) {
    stage_gemm(S, Uh, nullptr, t2h, nullptr, zh, nullptr, Uh, nullptr,
               znh, nullptr, znBh, nullptr, nullptr,
               256, 256, 256, -13.f, 15.f, -0.25f,
               blockIdx.x, blockIdx.y, batch, threadIdx.x);
  } else {
    stage_gemm(S, Y2h, nullptr, t2h, nullptr, Yh, nullptr, Y2h, nullptr,
               Ynh, nullptr, nullptr, nullptr, nullptr,
               256, 256, 256, -13.f, 15.f, -0.25f,
               blockIdx.x, blockIdx.y, batch, threadIdx.x);
  }
}

// ---------------------------------------------------------------------------
// K6: sim3 flash via MFMA, no max-subtraction (scores tiny). n-split NCH ways.
// ---------------------------------------------------------------------------
constexpr int NCH = 4;
__global__ __launch_bounds__(256) void sim3_mfma(const float* __restrict__ qlm,
                                                 const ush* __restrict__ k_bf,
                                                 const ush* __restrict__ vT_bf,
                                                 float* __restrict__ O_part,
                                                 float* __restrict__ l_part) {
  constexpr int CHUNK = SEQ / NCH;  // 1024
  __shared__ ush Qs[64][72];
  __shared__ ush Ks[128][72];
  __shared__ ush Vs[64][136];
  __shared__ ush Ps[64][136];
  const int bh = blockIdx.z;
  const int m0 = blockIdx.x * 64;
  const int n_base = blockIdx.y * CHUNK;
  const int tid = threadIdx.x;
  const int w = tid >> 6, lane = tid & 63;
  const int lm = lane & 15, lq = lane >> 4;
  {
    int m = tid >> 2, off = (tid & 3) * 16;
    const float* src = &qlm[((size_t)bh * NLM + m0 + m) * HD + off];
    us8 o0, o1;
#pragma unroll
    for (int j = 0; j < 8; ++j) o0[j] = f2bf(src[j]);
#pragma unroll
    for (int j = 0; j < 8; ++j) o1[j] = f2bf(src[8 + j]);
    *(us8*)&Qs[m][off] = o0;
    *(us8*)&Qs[m][off + 8] = o1;
  }
  const ffrag fz = {0.f, 0.f, 0.f, 0.f};
  ffrag O[4] = {fz, fz, fz, fz};
  float lsum[4] = {0.f, 0.f, 0.f, 0.f};

  for (int n0 = 0; n0 < CHUNK; n0 += 128) {
    __syncthreads();
    {
      int n = tid >> 1, off = (tid & 1) * 32;
      const ush* src = &k_bf[((size_t)bh * SEQ + n_base + n0 + n) * HD + off];
#pragma unroll
      for (int u = 0; u < 4; ++u) *(us8*)&Ks[n][off + 8 * u] = *(const us8*)&src[8 * u];
    }
    {
      int d = tid >> 2, off = (tid & 3) * 32;
      const ush* src = &vT_bf[((size_t)bh * HD + d) * SEQ + n_base + n0 + off];
#pragma unroll
      for (int u = 0; u < 4; ++u) *(us8*)&Vs[d][off + 8 * u] = *(const us8*)&src[8 * u];
    }
    __syncthreads();
    ffrag S[8] = {fz, fz, fz, fz, fz, fz, fz, fz};
#pragma unroll
    for (int ks = 0; ks < 2; ++ks) {
      bfrag a = *(const bfrag*)&Qs[16 * w + lm][32 * ks + 8 * lq];
#pragma unroll
      for (int t = 0; t < 8; ++t) {
        bfrag b = *(const bfrag*)&Ks[16 * t + lm][32 * ks + 8 * lq];
        S[t] = __builtin_amdgcn_mfma_f32_16x16x32_bf16(a, b, S[t], 0, 0, 0);
      }
    }
#pragma unroll
    for (int t = 0; t < 8; ++t)
#pragma unroll
      for (int r = 0; r < 4; ++r) {
        float p = __expf(S[t][r]);
        lsum[r] += p;
        Ps[16 * w + 4 * lq + r][16 * t + lm] = f2bf(p);
      }
    __syncthreads();
#pragma unroll
    for (int kk = 0; kk < 4; ++kk) {
      bfrag a = *(const bfrag*)&Ps[16 * w + lm][32 * kk + 8 * lq];
#pragma unroll
      for (int t2 = 0; t2 < 4; ++t2) {
        bfrag b = *(const bfrag*)&Vs[16 * t2 + lm][32 * kk + 8 * lq];
        O[t2] = __builtin_amdgcn_mfma_f32_16x16x32_bf16(a, b, O[t2], 0, 0, 0);
      }
    }
  }
#pragma unroll
  for (int r = 0; r < 4; ++r) {
#pragma unroll
    for (int off = 1; off < 16; off <<= 1) lsum[r] += __shfl_xor(lsum[r], off);
  }
  const size_t pbase = (size_t)blockIdx.y * 32 + bh;
  if (lm == 0) {
#pragma unroll
    for (int r = 0; r < 4; ++r)
      l_part[pbase * NLM + m0 + 16 * w + 4 * lq + r] = lsum[r];
  }
#pragma unroll
  for (int t2 = 0; t2 < 4; ++t2)
#pragma unroll
    for (int r = 0; r < 4; ++r) {
      int m = m0 + 16 * w + 4 * lq + r;
      int d = 16 * t2 + lm;
      O_part[(pbase * NLM + m) * HD + d] = O[t2][r];
    }
}

// sim3_finalize: combine partials, write sv in B-form split ([d][m]).
// grid (8,32): blockIdx.x = {d-quarter (low 2 bits), m-half (bit 2)}.
__global__ __launch_bounds__(256) void sim3_finalize(const float* __restrict__ O_part,
                                                     const float* __restrict__ l_part,
                                                     ush* __restrict__ svBh,
                                                     ush* __restrict__ svBl) {
  __shared__ float T[128][17];
  __shared__ float ls[128];
  const int bh = blockIdx.y;
  const int d0 = (blockIdx.x & 3) * 16;
  const int m0 = (blockIdx.x >> 2) * 128;
  const int tid = threadIdx.x;
  if (tid < 128) {
    float s = 0.f;
#pragma unroll
    for (int c = 0; c < NCH; ++c) s += l_part[(size_t)(c * 32 + bh) * NLM + m0 + tid];
    ls[tid] = s;
  }
#pragma unroll
  for (int i = 0; i < 8; ++i) {
    int e = i * 256 + tid;          // [0, 2048)
    int m = e >> 4, dd = e & 15;
    float s = 0.f;
#pragma unroll
    for (int c = 0; c < NCH; ++c)
      s += O_part[(((size_t)(c * 32 + bh)) << 14) + (size_t)(m0 + m) * HD + d0 + dd];
    T[m][dd] = s;
  }
  __syncthreads();
#pragma unroll
  for (int i = 0; i < 8; ++i) {
    int e = i * 256 + tid;
    int dd = e >> 7, m = e & 127;
    float val = T[m][dd] / ls[m];
    ush h, l; splitf(val, h, l);
    size_t o = ((size_t)bh * HD + d0 + dd) * NLM + m0 + m;
    svBh[o] = h; svBl[o] = l;
  }
}

// ---------------------------------------------------------------------------
// K8: attn1 via MFMA: outp = softmax(q_bf @ klm^T) @ tt  (fp32 softmax)
// ---------------------------------------------------------------------------
__global__ __launch_bounds__(256) void attn1_mfma(const ush* __restrict__ q_bf,
                                                  const float* __restrict__ klm,
                                                  const ush* __restrict__ ttT,
                                                  float* __restrict__ outp) {
  __shared__ ush bufA[256 * 72];   // klm bf16 [256][72] then ttT [64][264]
  __shared__ ush bufB[64 * 264];   // qs [64][72] then Ps [64][264]
  const int bh = blockIdx.y;
  const int b = bh >> 3, h = bh & 7;
  const int i0 = blockIdx.x * 64;
  const int tid = threadIdx.x;
  const int w = tid >> 6, lane = tid & 63;
  const int lm = lane & 15, lq = lane >> 4;
  {
    int m = tid >> 2, off = (tid & 3) * 16;
    const ush* src = &q_bf[((size_t)bh * SEQ + i0 + m) * HD + off];
    *(us8*)&bufB[m * 72 + off] = *(const us8*)src;
    *(us8*)&bufB[m * 72 + off + 8] = *(const us8*)&src[8];
  }
  {
    const float* kb = klm + (size_t)bh * NLM * HD;
#pragma unroll
    for (int u = 0; u < 16; ++u) {
      int e4 = u * 256 + tid;
      float4 f = ((const float4*)kb)[e4];
      int row = e4 >> 4, col = (e4 & 15) * 4;
      ush* p = &bufA[row * 72 + col];
      p[0] = f2bf(f.x); p[1] = f2bf(f.y); p[2] = f2bf(f.z); p[3] = f2bf(f.w);
    }
  }
  __syncthreads();
  const ffrag fz = {0.f, 0.f, 0.f, 0.f};
  ffrag S[16];
#pragma unroll
  for (int t = 0; t < 16; ++t) S[t] = fz;
#pragma unroll
  for (int ks = 0; ks < 2; ++ks) {
    bfrag a = *(const bfrag*)&bufB[(16 * w + lm) * 72 + 32 * ks + 8 * lq];
#pragma unroll
    for (int t = 0; t < 16; ++t) {
      bfrag bb = *(const bfrag*)&bufA[(16 * t + lm) * 72 + 32 * ks + 8 * lq];
      S[t] = __builtin_amdgcn_mfma_f32_16x16x32_bf16(a, bb, S[t], 0, 0, 0);
    }
  }
  float rinv[4];
  float ev[16][4];
#pragma unroll
  for (int r = 0; r < 4; ++r) {
    float mx = -INFINITY;
#pragma unroll
    for (int t = 0; t < 16; ++t) mx = fmaxf(mx, S[t][r]);
#pragma unroll
    for (int off = 1; off < 16; off <<= 1) mx = fmaxf(mx, __shfl_xor(mx, off));
    float sm = 0.f;
#pragma unroll
    for (int t = 0; t < 16; ++t) { ev[t][r] = __expf(S[t][r] - mx); sm += ev[t][r]; }
#pragma unroll
    for (int off = 1; off < 16; off <<= 1) sm += __shfl_xor(sm, off);
    rinv[r] = 1.0f / sm;
  }
  __syncthreads();
#pragma unroll
  for (int t = 0; t < 16; ++t)
#pragma unroll
    for (int r = 0; r < 4; ++r)
      bufB[(16 * w + 4 * lq + r) * 264 + 16 * t + lm] = f2bf(ev[t][r]);
  {
    const ush* tb = ttT + (size_t)bh * HD * NLM;
#pragma unroll
    for (int u = 0; u < 8; ++u) {
      int e8 = u * 256 + tid;
      int row = e8 >> 5, col = (e8 & 31) * 8;
      *(us8*)&bufA[row * 264 + col] = *(const us8*)&tb[row * NLM + col];
    }
  }
  __syncthreads();
  ffrag O[4] = {fz, fz, fz, fz};
#pragma unroll
  for (int kk = 0; kk < 8; ++kk) {
    bfrag a = *(const bfrag*)&bufB[(16 * w + lm) * 264 + 32 * kk + 8 * lq];
#pragma unroll
    for (int t2 = 0; t2 < 4; ++t2) {
      bfrag bb = *(const bfrag*)&bufA[(16 * t2 + lm) * 264 + 32 * kk + 8 * lq];
      O[t2] = __builtin_amdgcn_mfma_f32_16x16x32_bf16(a, bb, O[t2], 0, 0, 0);
    }
  }
#pragma unroll
  for (int t2 = 0; t2 < 4; ++t2)
#pragma unroll
    for (int r = 0; r < 4; ++r) {
      int i = i0 + 16 * w + 4 * lq + r;
      int d = 16 * t2 + lm;
      outp[((size_t)b * SEQ + i) * DIMC + h * HD + d] = O[t2][r] * rinv[r];
    }
}

// ---------------------------------------------------------------------------
// K9: conv add + split: outp(fp32) + depthwise conv(vT) -> outph/outpl
// ---------------------------------------------------------------------------
__global__ __launch_bounds__(256) void conv_add_split(const float* __restrict__ outp,
                                                      const ush* __restrict__ vT,
                                                      const float* __restrict__ kern,
                                                      ush* __restrict__ oh,
                                                      ush* __restrict__ ol) {
  __shared__ float vt[64 * 97];   // [d][96+1], cols n0-16 .. n0+79
  __shared__ float ks[KWIN];
  const int bh = blockIdx.y;
  const int b = bh >> 3, hh = bh & 7;
  const int n0 = blockIdx.x * 64;
  const int tid = threadIdx.x;
  if (tid < KWIN) ks[tid] = kern[hh * KWIN + tid];
  for (int e = tid; e < 64 * 96; e += 256) {
    int d = e / 96, c = e % 96;
    int n = n0 - 16 + c;
    vt[d * 97 + c] = (n >= 0 && n < SEQ) ? bf2f(vT[((size_t)bh * HD + d) * SEQ + n]) : 0.f;
  }
  __syncthreads();
  const int d = tid & 63, g = tid >> 6;
  float wreg[48];
#pragma unroll
  for (int j = 0; j < 48; ++j) wreg[j] = vt[d * 97 + g * 16 + j];
#pragma unroll
  for (int nn = 0; nn < 16; ++nn) {
    float s = 0.f;
#pragma unroll
    for (int t = 0; t < KWIN; ++t) s = fmaf(ks[t], wreg[nn + t], s);
    int n = n0 + g * 16 + nn;
    size_t o = ((size_t)b * SEQ + n) * DIMC + hh * HD + d;
    float val = outp[o] + s;
    ush h, l; splitf(val, h, l);
    oh[o] = h; ol[o] = l;
  }
}

// ---------------------------------------------------------------------------
// K10: out = outp_split @ WoutT_split + bias (3-product: final projection is
// precision-critical, keep full split). BM=BN=128, grid (128, 4)
// ---------------------------------------------------------------------------
__global__ __launch_bounds__(256) void out_gemm_split(const ush* __restrict__ ah_g,
                                                      const ush* __restrict__ al_g,
                                                      const ush* __restrict__ bh_g,
                                                      const ush* __restrict__ bl_g,
                                                      const float* __restrict__ bias,
                                                      float* __restrict__ out) {
  __shared__ ush Ash[128][40], Asl[128][40];
  __shared__ ush Bsh[128][40], Bsl[128][40];
  const int tid = threadIdx.x;
  const int w = tid >> 6, lane = tid & 63;
  const int lm = lane & 15, lq = lane >> 4;
  const int wm = w >> 1, wn = w & 1;
  const int row0 = blockIdx.x * 128, col0 = blockIdx.y * 128;
  const ffrag fz = {0.f, 0.f, 0.f, 0.f};
  ffrag acc[4][4];
#pragma unroll
  for (int i = 0; i < 4; ++i)
#pragma unroll
    for (int j = 0; j < 4; ++j) acc[i][j] = fz;

  const int sm = tid >> 1, skoff = (tid & 1) * 16;
  for (int k0 = 0; k0 < 512; k0 += 32) {
    __syncthreads();
    {
      size_t ao = (size_t)(row0 + sm) * 512 + k0 + skoff;
      *(us8*)&Ash[sm][skoff]     = *(const us8*)&ah_g[ao];
      *(us8*)&Ash[sm][skoff + 8] = *(const us8*)&ah_g[ao + 8];
      *(us8*)&Asl[sm][skoff]     = *(const us8*)&al_g[ao];
      *(us8*)&Asl[sm][skoff + 8] = *(const us8*)&al_g[ao + 8];
      size_t bo = (size_t)(col0 + sm) * 512 + k0 + skoff;
      *(us8*)&Bsh[sm][skoff]     = *(const us8*)&bh_g[bo];
      *(us8*)&Bsh[sm][skoff + 8] = *(const us8*)&bh_g[bo + 8];
      *(us8*)&Bsl[sm][skoff]     = *(const us8*)&bl_g[bo];
      *(us8*)&Bsl[sm][skoff + 8] = *(const us8*)&bl_g[bo + 8];
    }
    __syncthreads();
    bfrag ah[4], al[4], bh[4], bl[4];
#pragma unroll
    for (int mt = 0; mt < 4; ++mt) {
      ah[mt] = *(const bfrag*)&Ash[64 * wm + 16 * mt + lm][8 * lq];
      al[mt] = *(const bfrag*)&Asl[64 * wm + 16 * mt + lm][8 * lq];
    }
#pragma unroll
    for (int nt = 0; nt < 4; ++nt) {
      bh[nt] = *(const bfrag*)&Bsh[64 * wn + 16 * nt + lm][8 * lq];
      bl[nt] = *(const bfrag*)&Bsl[64 * wn + 16 * nt + lm][8 * lq];
    }
#pragma unroll
    for (int mt = 0; mt < 4; ++mt)
#pragma unroll
      for (int nt = 0; nt < 4; ++nt) {
        acc[mt][nt] = __builtin_amdgcn_mfma_f32_16x16x32_bf16(ah[mt], bh[nt], acc[mt][nt], 0, 0, 0);
        acc[mt][nt] = __builtin_amdgcn_mfma_f32_16x16x32_bf16(al[mt], bh[nt], acc[mt][nt], 0, 0, 0);
        acc[mt][nt] = __builtin_amdgcn_mfma_f32_16x16x32_bf16(ah[mt], bl[nt], acc[mt][nt], 0, 0, 0);
      }
  }
#pragma unroll
  for (int mt = 0; mt < 4; ++mt)
#pragma unroll
    for (int nt = 0; nt < 4; ++nt) {
      int n = col0 + 64 * wn + 16 * nt + lm;
      float bv = bias[n];
#pragma unroll
      for (int r = 0; r < 4; ++r) {
        int m = row0 + 64 * wm + 16 * mt + 4 * lq + r;
        out[(size_t)m * 512 + n] = acc[mt][nt][r] + bv;
      }
    }
}

// ---------------------------------------------------------------------------
extern "C" void kernel_launch(void* const* d_in, const int* in_sizes, int n_in,
                              void* d_out, int out_size, void* d_ws, size_t ws_size,
                              hipStream_t stream) {
  const float* x    = (const float*)d_in[0];
  const float* Wqkv = (const float*)d_in[1];
  const float* Wout = (const float*)d_in[2];
  const float* bout = (const float*)d_in[3];
  const float* rker = (const float*)d_in[4];
  float* out = (float*)d_out;
  float* ws = (float*)d_ws;

  // workspace layout (float-element offsets), total ~186.6 MB
  ush*   vT     = (ush*)(ws);                          // 8388608 ush (v transposed)
  ush*   q_bf   = (ush*)(ws + 4194304);                // 8388608 ush
  float* regA   = ws + 8388608;                        // 8388608 f: k_bf -> outp
  float* regB   = ws + 16777216;                       // 8388608 f: xh+xl -> outph+outpl
  float* qlm    = ws + 25165824;                       // 524288
  float* klm    = ws + 25690112;                       // 524288
  float* regC   = ws + 26214400;                       // 2097152 f: t2(h,l) / ttT
  float* a2reg  = ws + 28311552;                       // 2097152 f: a2h+a2l
  float* zAreg  = ws + 30408704;                       // 4194304 f
  float* zBreg  = ws + 34603008;                       // 4194304 f
  float* xzreg  = ws + 38797312;                       // 4194304 f: Y ping-pong (later O_part/l_part)
  float* t3reg  = ws + 43515904;                       // 2097152 f: U + Y2 (later svB)
  float* wqkvT  = ws + 45613056;                       // 786432 f
  float* woutT  = ws + 46399488;                       // 262144 f
  float* red    = ws + 46661632;                       // 128

  ush* k_bf  = (ush*)regA;
  float* outp = regA;
  ush* xh = (ush*)regB;                 // 8388608 ush
  ush* xl = (ush*)(regB + 4194304);     // 8388608 ush
  ush* outph = (ush*)regB;
  ush* outpl = (ush*)(regB + 4194304);
  ush* a2h = (ush*)a2reg;               // 2097152 ush each
  ush* a2l = (ush*)(a2reg + 1048576);
  ush* zA_[4] = {(ush*)zAreg, (ush*)(zAreg + 1048576), (ush*)(zAreg + 2097152), (ush*)(zAreg + 3145728)};
  ush* zB_[4] = {(ush*)zBreg, (ush*)(zBreg + 1048576), (ush*)(zBreg + 2097152), (ush*)(zBreg + 3145728)};
  ush* Y_h  = (ush*)xzreg;              // Y ping-pong (hi); lo slot doubles as ping B
  ush* Y_l  = (ush*)(xzreg + 1048576);  //   during plain carry-Y iters (lo dead)
  ush* t2_h = (ush*)regC;               // t2 = 7Y - Y^2, symmetric (row-major)
  ush* t2_l = (ush*)(regC + 1048576);
  ush* U_h  = (ush*)t3reg;              // U = z@Y (row-major)
  ush* U_l  = (ush*)(t3reg + 1048576);  // split iters: U lo; plain iters: Y2
  ush* Y2_h = U_l;                      // Y^2 (raw C tap) during plain iters
  float* O_part = xzreg;                // after pinv
  float* l_part = xzreg + 2097152;
  ush* svB_h = (ush*)t3reg;             // after pinv
  ush* svB_l = (ush*)(t3reg + 262144);
  ush* ttT   = (ush*)regC;              // after pinv
  ush* wqkvT_h = (ush*)wqkvT;
  ush* wqkvT_l = (ush*)(wqkvT + 393216);
  ush* woutT_h = (ush*)woutT;
  ush* woutT_l = (ush*)(woutT + 131072);

  // --- pre-splits ---
  split_flat<<<2048, 256, 0, stream>>>(x, xh, xl, 2097152);
  transpose_split_w<<<dim3(48, 16), 256, 0, stream>>>(Wqkv, wqkvT_h, wqkvT_l, 512, 1536);
  transpose_split_w<<<dim3(16, 16), 256, 0, stream>>>(Wout, woutT_h, woutT_l, 512, 512);

  // --- qkv + landmarks (+ direct vT) ---
  qkv_mfma<<<dim3(128, 12), 256, 0, stream>>>(xh, xl, wqkvT_h,
                                              q_bf, k_bf, vT, qlm, klm);

  // --- attn2 + pinv init ---
  sim2_softmax<<<8192, 256, 0, stream>>>(qlm, klm, a2h, a2l);
  colmax<<<32, 256, 0, stream>>>(a2h, red);
  finalize_scale<<<1, 64, 0, stream>>>(red);
  zinit_split<<<dim3(8, 8, 32), 256, 0, stream>>>(a2h, a2l, red,
                                                  zA_[0], zA_[1], zA_[2], zA_[3]);

  // --- pinv Newton-Schulz (launch-synchronized; r4/r5: never re-fuse) ---
  // Plain iters 0-3: carry-Y, 2 launches/iter (depth-minimum, r7/r8-verified).
  // Iters 4-5: proven 3-stage split path, Y recomputed fresh from a2@z.
  ush** zc = zA_;
  ush** zn = zB_;
  ush* Yc = Y_h;
  ush* Yn = Y_l;   // lo slot dead during plain iters -> Y ping B
  // Y0 = a2 @ z0 (plain)
  bgemm_split<<<dim3(4, 4, 32), 256, 0, stream>>>(
      a2h, nullptr, zc[2], nullptr,
      nullptr, nullptr, nullptr, nullptr,
      Yc, nullptr, nullptr, nullptr,
      256, 256, 256, 0.f, 0.f, -1.f);
  for (int it = 0; it < 4; ++it) {
    ns_sa<<<dim3(4, 4, 64), 256, 0, stream>>>(Yc, zc[0], t2_h, Y2_h, U_h);
    ns_sb<<<dim3(4, 4, 64), 256, 0, stream>>>(zc[0], U_h, t2_h, Yc, Y2_h,
                                              zn[0], zn[2], Yn);
    ush** tp = zc; zc = zn; zn = tp;
    ush* ty = Yc; Yc = Yn; Yn = ty;
  }
  for (int it = 4; it < 6; ++it) {
    const bool zin_s = (it == 5);
    // S1: Y = a2 @ z (full split, fresh consistency)
    bgemm_split<<<dim3(4, 4, 32), 256, 0, stream>>>(
        a2h, a2l, zc[2], zin_s ? zc[3] : nullptr,
        nullptr, nullptr, nullptr, nullptr,
        Y_h, Y_l, nullptr, nullptr,
        256, 256, 256, 0.f, 0.f, -1.f);
    // S2: t2 = 7Y - Y@Y ; U = z@Y
    ns_s2<<<dim3(4, 4, 64), 256, 0, stream>>>(
        Y_h, Y_l, zc[0], zin_s ? zc[1] : nullptr,
        t2_h, t2_l, U_h, U_l);
    // S3: z' = 0.25*(13 z - 15 U + U@t2)
    bgemm_split<<<dim3(4, 4, 32), 256, 0, stream>>>(
        U_h, U_l, t2_h, t2_l,
        zc[0], zin_s ? zc[1] : nullptr,
        U_h, U_l,
        zn[0], zn[1], zn[2], zn[3],
        256, 256, 256, -13.f, 15.f, -0.25f);
    ush** tp = zc; zc = zn; zn = tp;
  }
  // after 6 swaps zc == zA_ (attn2_inv, full split)

  // --- sim3 (flash) ---
  sim3_mfma<<<dim3(4, NCH, 32), 256, 0, stream>>>(qlm, k_bf, vT, O_part, l_part);
  sim3_finalize<<<dim3(8, 32), 256, 0, stream>>>(O_part, l_part, svB_h, svB_l);

  // --- tt = attn2_inv @ sv (write ttT = tt^T plain bf16) ---
  bgemm_split<<<dim3(4, 1, 32), 256, 0, stream>>>(
      zc[0], zc[1], svB_h, svB_l,
      nullptr, nullptr, nullptr, nullptr,
      nullptr, nullptr, ttT, nullptr, 256, 64, 256, 0.f, 0.f, -1.f);

  // --- attn1 + conv + output projection ---
  attn1_mfma<<<dim3(64, 32), 256, 0, stream>>>(q_bf, klm, ttT, outp);
  conv_add_split<<<dim3(64, 32), 256, 0, stream>>>(outp, vT, rker, outph, outpl);
  out_gemm_split<<<dim3(128, 4), 256, 0, stream>>>(outph, outpl, woutT_h, woutT_l, bout, out);
}

// Round 10
// 653.243 us; speedup vs baseline: 1.1733x; 1.0732x over previous
//
#include <hip/hip_runtime.h>
#include <math.h>

// Problem constants
constexpr int BATCH = 4;
constexpr int SEQ   = 4096;
constexpr int DIMC  = 512;
constexpr int NH    = 8;
constexpr int HD    = 64;
constexpr int NLM   = 256;   // landmarks M
constexpr int LWIN  = 16;    // SEQ / NLM
constexpr int KWIN  = 33;
constexpr int BH    = BATCH * NH; // 32

typedef __attribute__((ext_vector_type(8))) short  bfrag;  // 8 bf16 for MFMA A/B
typedef __attribute__((ext_vector_type(4))) float  ffrag;  // MFMA C/D
typedef __attribute__((ext_vector_type(8))) unsigned short us8;
typedef __attribute__((ext_vector_type(4))) unsigned short us4;
typedef unsigned short ush;

__device__ __forceinline__ ush f2bf(float f) {
  unsigned u = __builtin_bit_cast(unsigned, f);
  return (ush)((u + 0x7FFFu + ((u >> 16) & 1u)) >> 16);
}
__device__ __forceinline__ float bf2f(ush h) {
  unsigned u = ((unsigned)h) << 16;
  return __builtin_bit_cast(float, u);
}
__device__ __forceinline__ void splitf(float f, ush& h, ush& l) {
  h = f2bf(f);
  l = f2bf(f - bf2f(h));
}

// ---------------------------------------------------------------------------
// split_flat: fp32 -> (hi, lo) bf16, elementwise (x pre-split). Grid-stride.
// ---------------------------------------------------------------------------
__global__ void split_flat(const float* __restrict__ src, ush* __restrict__ oh,
                           ush* __restrict__ ol, int n4) {
  for (int i = blockIdx.x * 256 + threadIdx.x; i < n4; i += gridDim.x * 256) {
    float4 f = ((const float4*)src)[i];
    us4 h, l;
    float fs[4] = {f.x, f.y, f.z, f.w};
#pragma unroll
    for (int j = 0; j < 4; ++j) {
      ush hh, ll;
      splitf(fs[j], hh, ll);
      h[j] = hh; l[j] = ll;
    }
    ((us4*)oh)[i] = h;
    ((us4*)ol)[i] = l;
  }
}

// ---------------------------------------------------------------------------
// transpose_split_w2: BOTH weight transposes in one launch (r10: -1 launch).
// z=0: Wqkv [512][1536]; z=1: Wout [512][512] (only bx<16 active).
// ---------------------------------------------------------------------------
__global__ __launch_bounds__(256) void transpose_split_w2(
    const float* __restrict__ inA, ush* __restrict__ oAh, ush* __restrict__ oAl,
    int CA,
    const float* __restrict__ inB, ush* __restrict__ oBh, ush* __restrict__ oBl,
    int CB) {
  const int which = blockIdx.z;
  if (which == 1 && blockIdx.x >= 16) return;
  const float* in = which ? inB : inA;
  ush* oh = which ? oBh : oAh;
  ush* ol = which ? oBl : oAl;
  const int C = which ? CB : CA;
  const int R = 512;
  __shared__ float T[32][33];
  const int tid = threadIdx.x;
  const int c0 = blockIdx.x * 32, r0 = blockIdx.y * 32;
#pragma unroll
  for (int u = 0; u < 4; ++u) {
    int r = (tid >> 5) * 4 + u, cl = tid & 31;
    T[r][cl] = in[(size_t)(r0 + r) * C + c0 + cl];
  }
  __syncthreads();
#pragma unroll
  for (int u = 0; u < 4; ++u) {
    int cl = (tid >> 5) * 4 + u, rl = tid & 31;
    float f = T[rl][cl];
    ush h, l; splitf(f, h, l);
    size_t o = (size_t)(c0 + cl) * R + r0 + rl;
    oh[o] = h; ol[o] = l;
  }
}

// ---------------------------------------------------------------------------
// K1: qkv MFMA GEMM — r9 form (CLOSED: us8 staging 83us >> DMA 136-144us;
// conflicts off critical path). Fragment-major LDS [plane][chunk][128][8],
// BK=32, 24KB. 2-product split. Epilogue: q/k + landmarks; vT direct.
// ---------------------------------------------------------------------------
__global__ __launch_bounds__(256) void qkv_mfma(const ush* __restrict__ xh,
                                                const ush* __restrict__ xl,
                                                const ush* __restrict__ wTh,
                                                ush* __restrict__ q_bf,
                                                ush* __restrict__ k_bf,
                                                ush* __restrict__ vT,
                                                float* __restrict__ qlm,
                                                float* __restrict__ klm) {
  __shared__ ush S[3][4][128][8];   // 24 KB fragment-major: {xh, xl, wTh}
  const int tid = threadIdx.x;
  const int w = tid >> 6, lane = tid & 63;
  const int lm = lane & 15, lq = lane >> 4;
  const int wm = w >> 1, wn = w & 1;
  const int row0 = blockIdx.x * 128, col0 = blockIdx.y * 128;
  const ffrag fz = {0.f, 0.f, 0.f, 0.f};
  ffrag acc[4][4];
#pragma unroll
  for (int i = 0; i < 4; ++i)
#pragma unroll
    for (int j = 0; j < 4; ++j) acc[i][j] = fz;

  const int sm = tid >> 1, hf = tid & 1;   // row 0..127, k-half 0..1
  for (int k0 = 0; k0 < 512; k0 += 32) {
    __syncthreads();
    {
      size_t ao = (size_t)(row0 + sm) * 512 + k0 + 16 * hf;
      us8 a0 = *(const us8*)&xh[ao];
      us8 a1 = *(const us8*)&xh[ao + 8];
      us8 l0 = *(const us8*)&xl[ao];
      us8 l1 = *(const us8*)&xl[ao + 8];
      size_t bo = (size_t)(col0 + sm) * 512 + k0 + 16 * hf;
      us8 b0 = *(const us8*)&wTh[bo];
      us8 b1 = *(const us8*)&wTh[bo + 8];
      *(us8*)&S[0][2 * hf][sm][0]     = a0;
      *(us8*)&S[0][2 * hf + 1][sm][0] = a1;
      *(us8*)&S[1][2 * hf][sm][0]     = l0;
      *(us8*)&S[1][2 * hf + 1][sm][0] = l1;
      *(us8*)&S[2][2 * hf][sm][0]     = b0;
      *(us8*)&S[2][2 * hf + 1][sm][0] = b1;
    }
    __syncthreads();
    bfrag ah[4], al[4], bh[4];
#pragma unroll
    for (int mt = 0; mt < 4; ++mt) {
      ah[mt] = *(const bfrag*)&S[0][lq][64 * wm + 16 * mt + lm][0];
      al[mt] = *(const bfrag*)&S[1][lq][64 * wm + 16 * mt + lm][0];
    }
#pragma unroll
    for (int nt = 0; nt < 4; ++nt)
      bh[nt] = *(const bfrag*)&S[2][lq][64 * wn + 16 * nt + lm][0];
#pragma unroll
    for (int mt = 0; mt < 4; ++mt)
#pragma unroll
      for (int nt = 0; nt < 4; ++nt) {
        acc[mt][nt] = __builtin_amdgcn_mfma_f32_16x16x32_bf16(ah[mt], bh[nt], acc[mt][nt], 0, 0, 0);
        acc[mt][nt] = __builtin_amdgcn_mfma_f32_16x16x32_bf16(al[mt], bh[nt], acc[mt][nt], 0, 0, 0);
      }
  }
  // epilogue (unchanged, r4-r9 verified)
#pragma unroll
  for (int mt = 0; mt < 4; ++mt) {
    int rbase = row0 + 64 * wm + 16 * mt;      // 16-aligned -> single window
    int b = rbase >> 12;
    int ntok_base = rbase & 4095;
    int win = ntok_base >> 4;
#pragma unroll
    for (int nt = 0; nt < 4; ++nt) {
      int n_local = 64 * wn + 16 * nt;          // frag col base (h uniform)
      int col = col0 + n_local + lm;
      int which = col >> 9;                     // 0=q 1=k 2=v
      int h = (col >> 6) & 7;
      int d = col & 63;
      int bh_i = b * NH + h;
      float scale = (which == 0) ? 0.125f : 1.0f;
      float vals[4];
      float s = 0.f;
#pragma unroll
      for (int r = 0; r < 4; ++r) {
        vals[r] = acc[mt][nt][r] * scale;
        s += vals[r];
      }
      if (which == 2) {
        ush* dst = &vT[((size_t)bh_i * HD + d) * SEQ + ntok_base + 4 * lq];
#pragma unroll
        for (int r = 0; r < 4; ++r) dst[r] = f2bf(vals[r]);
      } else {
        ush* dst = which == 0 ? q_bf : k_bf;
#pragma unroll
        for (int r = 0; r < 4; ++r) {
          int ntok = ntok_base + 4 * lq + r;
          dst[((size_t)bh_i * SEQ + ntok) * HD + d] = f2bf(vals[r]);
        }
        s += __shfl_xor(s, 16);
        s += __shfl_xor(s, 32);
        if (lq == 0) {
          float* lmdst = which == 0 ? qlm : klm;
          lmdst[((size_t)bh_i * NLM + win) * HD + d] = s * (1.0f / LWIN);
        }
      }
    }
  }
}

// ---------------------------------------------------------------------------
// K3: attn2 = softmax(qlm @ klm^T) rows -> split bf16. Block 0 also zeroes
// the colmax atomic slot (r10: finalize_scale launch deleted).
// ---------------------------------------------------------------------------
__global__ __launch_bounds__(256) void sim2_softmax(const float* __restrict__ qlm,
                                                    const float* __restrict__ klm,
                                                    ush* __restrict__ a2h,
                                                    ush* __restrict__ a2l,
                                                    float* __restrict__ red) {
  if (blockIdx.x == 0 && threadIdx.x == 0) ((unsigned*)red)[64] = 0u;
  int i = blockIdx.x & 255;
  int bh = blockIdx.x >> 8;
  int j = threadIdx.x;
  __shared__ float qrow[64];
  __shared__ float redl[256];
  if (j < 64) qrow[j] = qlm[((size_t)bh * NLM + i) * HD + j];
  __syncthreads();
  const float* kr = klm + ((size_t)bh * NLM + j) * HD;
  float s = 0.f;
#pragma unroll
  for (int d = 0; d < 64; d += 4) {
    float4 kv = *(const float4*)&kr[d];
    s += qrow[d] * kv.x + qrow[d + 1] * kv.y + qrow[d + 2] * kv.z + qrow[d + 3] * kv.w;
  }
  redl[j] = s; __syncthreads();
  for (int off = 128; off > 0; off >>= 1) {
    if (j < off) redl[j] = fmaxf(redl[j], redl[j + off]);
    __syncthreads();
  }
  float mx = redl[0]; __syncthreads();
  float e = expf(s - mx);
  redl[j] = e; __syncthreads();
  for (int off = 128; off > 0; off >>= 1) {
    if (j < off) redl[j] += redl[j + off];
    __syncthreads();
  }
  float val = e / redl[0];
  size_t o = ((size_t)bh * NLM + i) * NLM + j;
  ush h, l; splitf(val, h, l);
  a2h[o] = h; a2l[o] = l;
}

// ---------------------------------------------------------------------------
// K4a: per-bh column sums of attn2 (hi plane), block max, device atomicMax
// (uint-punned positive floats: bit order == value order -> exact max).
// attn2 rows are softmax rows -> row sums are exactly 1.
// ---------------------------------------------------------------------------
__global__ __launch_bounds__(256) void colmax(const ush* __restrict__ a2h,
                                              float* __restrict__ red) {
  int bh = blockIdx.x;
  int t = threadIdx.x;
  const size_t base = (size_t)bh * NLM * NLM;
  float cs = 0.f;
  for (int i = 0; i < NLM; ++i) cs += bf2f(a2h[base + (size_t)i * NLM + t]);
  __shared__ float r1[256];
  r1[t] = cs; __syncthreads();
  for (int off = 128; off > 0; off >>= 1) {
    if (t < off) r1[t] = fmaxf(r1[t], r1[t + off]);
    __syncthreads();
  }
  if (t == 0) atomicMax((unsigned*)red + 64, __float_as_uint(r1[0]));
}

// ---------------------------------------------------------------------------
// K4c: z0 = attn2^T * invscale, A-form + B-form splits. Computes 1/max
// itself from the colmax atomic slot (row-sum max == 1, softmax rows).
// ---------------------------------------------------------------------------
__global__ __launch_bounds__(256) void zinit_split(const ush* __restrict__ a2h,
                                                   const ush* __restrict__ a2l,
                                                   const float* __restrict__ red,
                                                   ush* __restrict__ zAh, ush* __restrict__ zAl,
                                                   ush* __restrict__ zBh, ush* __restrict__ zBl) {
  __shared__ float T[32][33];
  const int tid = threadIdx.x;
  const int bh = blockIdx.z;
  const int j0 = blockIdx.x * 32, i0 = blockIdx.y * 32;
  const float s = 1.0f / __uint_as_float(((const unsigned*)red)[64]);
  const size_t base = (size_t)bh * NLM * NLM;
#pragma unroll
  for (int u = 0; u < 4; ++u) {
    int jl = (tid >> 5) * 4 + u, il = tid & 31;
    size_t o = base + (size_t)(j0 + jl) * NLM + i0 + il;
    float a = (bf2f(a2h[o]) + bf2f(a2l[o])) * s;
    T[jl][il] = a;
    ush h, l; splitf(a, h, l);
    zBh[o] = h; zBl[o] = l;   // zB[j][i] = a2[j][i]*s
  }
  __syncthreads();
#pragma unroll
  for (int u = 0; u < 4; ++u) {
    int il = (tid >> 5) * 4 + u, jl = tid & 31;
    float a = T[jl][il];
    ush h, l; splitf(a, h, l);
    size_t o = base + (size_t)(i0 + il) * NLM + j0 + jl;  // zA[i][j] = a2[j][i]*s
    zAh[o] = h; zAl[o] = l;
  }
}

// ---------------------------------------------------------------------------
// K5 core: one 64x64 tile of C = A@B^T(stored), split-bf16 planes.
// ROUND-10: us8 VGPR staging (r7/r8/r9 finding: global_load_lds queue depth
// 4-8/wave is latency-bound at this scale; us8 keeps ~100s of loads in
// flight). Thread (op=tid>>7, row=(tid>>1)&63, cq=tid&1) loads 4 us8/plane,
// stores into the IDENTICAL fragment-major layout -> MFMA side and numerics
// bit-identical to the r3..r9 gl_lds version.
// Epilogue: y = coef*(alpha*E1 + beta*E2 - C); row-major (oA), B-form (oB),
// raw C tap (oC). FORCEINLINE ONLY (r2: noinline corrupted LDS addressing).
// NOTE (r4/r5): in-kernel barrier fusion is structurally HBM-bound — never
// re-fuse.
// ---------------------------------------------------------------------------
__device__ __forceinline__ void stage_gemm(
    ush (*S)[2][8][64][8],   // LDS [2][2][8][64][8] = 32 KB
    const ush* Ah, const ush* Al, const ush* Bh, const ush* Bl,
    const ush* E1h, const ush* E1l, const ush* E2h, const ush* E2l,
    ush* oAh, ush* oAl, ush* oBh, ush* oBl, ush* oCh,
    int M, int N, int K, float alpha, float beta, float coef,
    int bx, int by, int batch, int tid) {
  const size_t abase = (size_t)batch * M * K;
  const size_t bbase = (size_t)batch * N * K;
  const size_t ebase = (size_t)batch * M * N;
  const int w = tid >> 6, lane = tid & 63;
  const int lm = lane & 15, lq = lane >> 4;
  const int wm = w >> 1, wn = w & 1;
  const int row0 = bx * 64, col0 = by * 64;
  const bool uAl = (Al != nullptr);
  const bool uBl = (Bl != nullptr);
  const ffrag fz = {0.f, 0.f, 0.f, 0.f};
  ffrag acc[2][2] = {{fz, fz}, {fz, fz}};

  // us8 staging assignment: waves 0-1 stage A, waves 2-3 stage B.
  const int sop = tid >> 7;            // 0 = A, 1 = B
  const int sr  = (tid >> 1) & 63;     // row within 64-row tile
  const int scq = tid & 1;             // chunk-quad (k-half of 64)
  const ush* gh = sop ? Bh : Ah;
  const ush* gl = sop ? Bl : Al;
  const bool ul = sop ? uBl : uAl;
  const size_t srow = (sop ? bbase + (size_t)(col0 + sr) * K
                           : abase + (size_t)(row0 + sr) * K) + 32 * scq;

  for (int k0 = 0; k0 < K; k0 += 64) {
    __syncthreads();
    {
      us8 vh[4], vl[4];
#pragma unroll
      for (int j = 0; j < 4; ++j) vh[j] = *(const us8*)&gh[srow + k0 + 8 * j];
      if (ul) {
#pragma unroll
        for (int j = 0; j < 4; ++j) vl[j] = *(const us8*)&gl[srow + k0 + 8 * j];
      }
#pragma unroll
      for (int j = 0; j < 4; ++j) *(us8*)&S[sop][0][4 * scq + j][sr][0] = vh[j];
      if (ul) {
#pragma unroll
        for (int j = 0; j < 4; ++j) *(us8*)&S[sop][1][4 * scq + j][sr][0] = vl[j];
      }
    }
    __syncthreads();
#pragma unroll
    for (int ks = 0; ks < 2; ++ks) {
      bfrag ah[2], al[2], bhf[2], blf[2];
#pragma unroll
      for (int mt = 0; mt < 2; ++mt) {
        ah[mt] = *(const bfrag*)&S[0][0][4 * ks + lq][32 * wm + 16 * mt + lm][0];
        if (uAl) al[mt] = *(const bfrag*)&S[0][1][4 * ks + lq][32 * wm + 16 * mt + lm][0];
      }
#pragma unroll
      for (int nt = 0; nt < 2; ++nt) {
        bhf[nt] = *(const bfrag*)&S[1][0][4 * ks + lq][32 * wn + 16 * nt + lm][0];
        if (uBl) blf[nt] = *(const bfrag*)&S[1][1][4 * ks + lq][32 * wn + 16 * nt + lm][0];
      }
#pragma unroll
      for (int mt = 0; mt < 2; ++mt)
#pragma unroll
        for (int nt = 0; nt < 2; ++nt) {
          acc[mt][nt] = __builtin_amdgcn_mfma_f32_16x16x32_bf16(ah[mt], bhf[nt], acc[mt][nt], 0, 0, 0);
          if (uAl) acc[mt][nt] = __builtin_amdgcn_mfma_f32_16x16x32_bf16(al[mt], bhf[nt], acc[mt][nt], 0, 0, 0);
          if (uBl) acc[mt][nt] = __builtin_amdgcn_mfma_f32_16x16x32_bf16(ah[mt], blf[nt], acc[mt][nt], 0, 0, 0);
        }
    }
  }
#pragma unroll
  for (int mt = 0; mt < 2; ++mt)
#pragma unroll
    for (int nt = 0; nt < 2; ++nt) {
      int n = col0 + 32 * wn + 16 * nt + lm;
#pragma unroll
      for (int r = 0; r < 4; ++r) {
        int m = row0 + 32 * wm + 16 * mt + 4 * lq + r;
        float c = acc[mt][nt][r];
        float e = 0.f;
        size_t eo = ebase + (size_t)m * N + n;
        if (E1h) {
          float t = bf2f(E1h[eo]);
          if (E1l) t += bf2f(E1l[eo]);
          e += alpha * t;
        }
        if (E2h) {
          float t = bf2f(E2h[eo]);
          if (E2l) t += bf2f(E2l[eo]);
          e += beta * t;
        }
        float y = coef * (e - c);
        ush h, l; splitf(y, h, l);
        if (oAh) {
          size_t o = ebase + (size_t)m * N + n;
          oAh[o] = h;
          if (oAl) oAl[o] = l;
        }
        if (oBh) {
          size_t o = (size_t)batch * N * M + (size_t)n * M + m;
          oBh[o] = h;
          if (oBl) oBl[o] = l;
        }
        if (oCh) oCh[ebase + (size_t)m * N + n] = f2bf(c);
      }
    }
}

__global__ __launch_bounds__(256) void bgemm_split(
    const ush* Ah, const ush* Al, const ush* Bh, const ush* Bl,
    const ush* E1h, const ush* E1l, const ush* E2h, const ush* E2l,
    ush* oAh, ush* oAl, ush* oBh, ush* oBl,
    int M, int N, int K, float alpha, float beta, float coef) {
  __shared__ ush S[2][2][8][64][8];
  stage_gemm(S, Ah, Al, Bh, Bl, E1h, E1l, E2h, E2l, oAh, oAl, oBh, oBl,
             nullptr, M, N, K, alpha, beta, coef,
             blockIdx.x, blockIdx.y, blockIdx.z, threadIdx.x);
}

// ---------------------------------------------------------------------------
// ns_s2: batched stage-2 of the 3-stage split NS iteration (iters 4-5).
// blockIdx.z parity: even -> t2 = 7Y - Y@Y; odd -> U = z@Y. r3-verified.
// ---------------------------------------------------------------------------
__global__ __launch_bounds__(256) void ns_s2(
    const ush* Yh, const ush* Yl, const ush* zh, const ush* zl,
    ush* t2h, ush* t2l, ush* Uh, ush* Ul) {
  __shared__ ush S[2][2][8][64][8];
  const int bz = blockIdx.z, batch = bz >> 1;
  if ((bz & 1) == 0) {
    stage_gemm(S, Yh, Yl, Yh, Yl, Yh, Yl, nullptr, nullptr,
               t2h, t2l, nullptr, nullptr, nullptr,
               256, 256, 256, 7.f, 0.f, 1.f,
               blockIdx.x, blockIdx.y, batch, threadIdx.x);
  } else {
    stage_gemm(S, zh, zl, Yh, Yl, nullptr, nullptr, nullptr, nullptr,
               Uh, Ul, nullptr, nullptr, nullptr,
               256, 256, 256, 0.f, 0.f, -1.f,
               blockIdx.x, blockIdx.y, batch, threadIdx.x);
  }
}

// ---------------------------------------------------------------------------
// ns_sa / ns_sb: carry-Y plain iterations (2 launches/iter, depth-minimum;
// r7/r8/r9-verified, absmax bit-identical). Y carried as state:
//   Y' = a2 z' = 0.25(13Y - 15Y^2 + Y^2 t2)   [exact identity]
// ns_sa even: C=Y@Y -> t2 = 7Y - C (oA) AND Y2 = C raw (oC). odd: U = z@Y.
// ns_sb even: z' (row + B-form). odd: Y' (row; symmetric).
// Iters 4-5 recompute Y fresh (split path) -> carry drift annihilated.
// ---------------------------------------------------------------------------
__global__ __launch_bounds__(256) void ns_sa(
    const ush* Yh, const ush* zh, ush* t2h, ush* Y2h, ush* Uh) {
  __shared__ ush S[2][2][8][64][8];
  const int bz = blockIdx.z, batch = bz >> 1;
  if ((bz & 1) == 0) {
    stage_gemm(S, Yh, nullptr, Yh, nullptr, Yh, nullptr, nullptr, nullptr,
               t2h, nullptr, nullptr, nullptr, Y2h,
               256, 256, 256, 7.f, 0.f, 1.f,
               blockIdx.x, blockIdx.y, batch, threadIdx.x);
  } else {
    stage_gemm(S, zh, nullptr, Yh, nullptr, nullptr, nullptr, nullptr, nullptr,
               Uh, nullptr, nullptr, nullptr, nullptr,
               256, 256, 256, 0.f, 0.f, -1.f,
               blockIdx.x, blockIdx.y, batch, threadIdx.x);
  }
}

__global__ __launch_bounds__(256) void ns_sb(
    const ush* zh, const ush* Uh, const ush* t2h,
    const ush* Yh, const ush* Y2h,
    ush* znh, ush* znBh, ush* Ynh) {
  __shared__ ush S[2][2][8][64][8];
  const int bz = blockIdx.z, batch = bz >> 1;
  if ((bz & 1) == 0) {
    stage_gemm(S, Uh, nullptr, t2h, nullptr, zh, nullptr, Uh, nullptr,
               znh, nullptr, znBh, nullptr, nullptr,
               256, 256, 256, -13.f, 15.f, -0.25f,
               blockIdx.x, blockIdx.y, batch, threadIdx.x);
  } else {
    stage_gemm(S, Y2h, nullptr, t2h, nullptr, Yh, nullptr, Y2h, nullptr,
               Ynh, nullptr, nullptr, nullptr, nullptr,
               256, 256, 256, -13.f, 15.f, -0.25f,
               blockIdx.x, blockIdx.y, batch, threadIdx.x);
  }
}

// ---------------------------------------------------------------------------
// K6: sim3 flash via MFMA, no max-subtraction (scores tiny). n-split NCH ways.
// ---------------------------------------------------------------------------
constexpr int NCH = 4;
__global__ __launch_bounds__(256) void sim3_mfma(const float* __restrict__ qlm,
                                                 const ush* __restrict__ k_bf,
                                                 const ush* __restrict__ vT_bf,
                                                 float* __restrict__ O_part,
                                                 float* __restrict__ l_part) {
  constexpr int CHUNK = SEQ / NCH;  // 1024
  __shared__ ush Qs[64][72];
  __shared__ ush Ks[128][72];
  __shared__ ush Vs[64][136];
  __shared__ ush Ps[64][136];
  const int bh = blockIdx.z;
  const int m0 = blockIdx.x * 64;
  const int n_base = blockIdx.y * CHUNK;
  const int tid = threadIdx.x;
  const int w = tid >> 6, lane = tid & 63;
  const int lm = lane & 15, lq = lane >> 4;
  {
    int m = tid >> 2, off = (tid & 3) * 16;
    const float* src = &qlm[((size_t)bh * NLM + m0 + m) * HD + off];
    us8 o0, o1;
#pragma unroll
    for (int j = 0; j < 8; ++j) o0[j] = f2bf(src[j]);
#pragma unroll
    for (int j = 0; j < 8; ++j) o1[j] = f2bf(src[8 + j]);
    *(us8*)&Qs[m][off] = o0;
    *(us8*)&Qs[m][off + 8] = o1;
  }
  const ffrag fz = {0.f, 0.f, 0.f, 0.f};
  ffrag O[4] = {fz, fz, fz, fz};
  float lsum[4] = {0.f, 0.f, 0.f, 0.f};

  for (int n0 = 0; n0 < CHUNK; n0 += 128) {
    __syncthreads();
    {
      int n = tid >> 1, off = (tid & 1) * 32;
      const ush* src = &k_bf[((size_t)bh * SEQ + n_base + n0 + n) * HD + off];
#pragma unroll
      for (int u = 0; u < 4; ++u) *(us8*)&Ks[n][off + 8 * u] = *(const us8*)&src[8 * u];
    }
    {
      int d = tid >> 2, off = (tid & 3) * 32;
      const ush* src = &vT_bf[((size_t)bh * HD + d) * SEQ + n_base + n0 + off];
#pragma unroll
      for (int u = 0; u < 4; ++u) *(us8*)&Vs[d][off + 8 * u] = *(const us8*)&src[8 * u];
    }
    __syncthreads();
    ffrag S[8] = {fz, fz, fz, fz, fz, fz, fz, fz};
#pragma unroll
    for (int ks = 0; ks < 2; ++ks) {
      bfrag a = *(const bfrag*)&Qs[16 * w + lm][32 * ks + 8 * lq];
#pragma unroll
      for (int t = 0; t < 8; ++t) {
        bfrag b = *(const bfrag*)&Ks[16 * t + lm][32 * ks + 8 * lq];
        S[t] = __builtin_amdgcn_mfma_f32_16x16x32_bf16(a, b, S[t], 0, 0, 0);
      }
    }
#pragma unroll
    for (int t = 0; t < 8; ++t)
#pragma unroll
      for (int r = 0; r < 4; ++r) {
        float p = __expf(S[t][r]);
        lsum[r] += p;
        Ps[16 * w + 4 * lq + r][16 * t + lm] = f2bf(p);
      }
    __syncthreads();
#pragma unroll
    for (int kk = 0; kk < 4; ++kk) {
      bfrag a = *(const bfrag*)&Ps[16 * w + lm][32 * kk + 8 * lq];
#pragma unroll
      for (int t2 = 0; t2 < 4; ++t2) {
        bfrag b = *(const bfrag*)&Vs[16 * t2 + lm][32 * kk + 8 * lq];
        O[t2] = __builtin_amdgcn_mfma_f32_16x16x32_bf16(a, b, O[t2], 0, 0, 0);
      }
    }
  }
#pragma unroll
  for (int r = 0; r < 4; ++r) {
#pragma unroll
    for (int off = 1; off < 16; off <<= 1) lsum[r] += __shfl_xor(lsum[r], off);
  }
  const size_t pbase = (size_t)blockIdx.y * 32 + bh;
  if (lm == 0) {
#pragma unroll
    for (int r = 0; r < 4; ++r)
      l_part[pbase * NLM + m0 + 16 * w + 4 * lq + r] = lsum[r];
  }
#pragma unroll
  for (int t2 = 0; t2 < 4; ++t2)
#pragma unroll
    for (int r = 0; r < 4; ++r) {
      int m = m0 + 16 * w + 4 * lq + r;
      int d = 16 * t2 + lm;
      O_part[(pbase * NLM + m) * HD + d] = O[t2][r];
    }
}

// sim3_finalize: combine partials, write sv in B-form split ([d][m]).
// grid (8,32): blockIdx.x = {d-quarter (low 2 bits), m-half (bit 2)}.
__global__ __launch_bounds__(256) void sim3_finalize(const float* __restrict__ O_part,
                                                     const float* __restrict__ l_part,
                                                     ush* __restrict__ svBh,
                                                     ush* __restrict__ svBl) {
  __shared__ float T[128][17];
  __shared__ float ls[128];
  const int bh = blockIdx.y;
  const int d0 = (blockIdx.x & 3) * 16;
  const int m0 = (blockIdx.x >> 2) * 128;
  const int tid = threadIdx.x;
  if (tid < 128) {
    float s = 0.f;
#pragma unroll
    for (int c = 0; c < NCH; ++c) s += l_part[(size_t)(c * 32 + bh) * NLM + m0 + tid];
    ls[tid] = s;
  }
#pragma unroll
  for (int i = 0; i < 8; ++i) {
    int e = i * 256 + tid;          // [0, 2048)
    int m = e >> 4, dd = e & 15;
    float s = 0.f;
#pragma unroll
    for (int c = 0; c < NCH; ++c)
      s += O_part[(((size_t)(c * 32 + bh)) << 14) + (size_t)(m0 + m) * HD + d0 + dd];
    T[m][dd] = s;
  }
  __syncthreads();
#pragma unroll
  for (int i = 0; i < 8; ++i) {
    int e = i * 256 + tid;
    int dd = e >> 7, m = e & 127;
    float val = T[m][dd] / ls[m];
    ush h, l; splitf(val, h, l);
    size_t o = ((size_t)bh * HD + d0 + dd) * NLM + m0 + m;
    svBh[o] = h; svBl[o] = l;
  }
}

// ---------------------------------------------------------------------------
// K8: attn1 via MFMA: outp = softmax(q_bf @ klm^T) @ tt  (fp32 softmax)
// ---------------------------------------------------------------------------
__global__ __launch_bounds__(256) void attn1_mfma(const ush* __restrict__ q_bf,
                                                  const float* __restrict__ klm,
                                                  const ush* __restrict__ ttT,
                                                  float* __restrict__ outp) {
  __shared__ ush bufA[256 * 72];   // klm bf16 [256][72] then ttT [64][264]
  __shared__ ush bufB[64 * 264];   // qs [64][72] then Ps [64][264]
  const int bh = blockIdx.y;
  const int b = bh >> 3, h = bh & 7;
  const int i0 = blockIdx.x * 64;
  const int tid = threadIdx.x;
  const int w = tid >> 6, lane = tid & 63;
  const int lm = lane & 15, lq = lane >> 4;
  {
    int m = tid >> 2, off = (tid & 3) * 16;
    const ush* src = &q_bf[((size_t)bh * SEQ + i0 + m) * HD + off];
    *(us8*)&bufB[m * 72 + off] = *(const us8*)src;
    *(us8*)&bufB[m * 72 + off + 8] = *(const us8*)&src[8];
  }
  {
    const float* kb = klm + (size_t)bh * NLM * HD;
#pragma unroll
    for (int u = 0; u < 16; ++u) {
      int e4 = u * 256 + tid;
      float4 f = ((const float4*)kb)[e4];
      int row = e4 >> 4, col = (e4 & 15) * 4;
      ush* p = &bufA[row * 72 + col];
      p[0] = f2bf(f.x); p[1] = f2bf(f.y); p[2] = f2bf(f.z); p[3] = f2bf(f.w);
    }
  }
  __syncthreads();
  const ffrag fz = {0.f, 0.f, 0.f, 0.f};
  ffrag S[16];
#pragma unroll
  for (int t = 0; t < 16; ++t) S[t] = fz;
#pragma unroll
  for (int ks = 0; ks < 2; ++ks) {
    bfrag a = *(const bfrag*)&bufB[(16 * w + lm) * 72 + 32 * ks + 8 * lq];
#pragma unroll
    for (int t = 0; t < 16; ++t) {
      bfrag bb = *(const bfrag*)&bufA[(16 * t + lm) * 72 + 32 * ks + 8 * lq];
      S[t] = __builtin_amdgcn_mfma_f32_16x16x32_bf16(a, bb, S[t], 0, 0, 0);
    }
  }
  float rinv[4];
  float ev[16][4];
#pragma unroll
  for (int r = 0; r < 4; ++r) {
    float mx = -INFINITY;
#pragma unroll
    for (int t = 0; t < 16; ++t) mx = fmaxf(mx, S[t][r]);
#pragma unroll
    for (int off = 1; off < 16; off <<= 1) mx = fmaxf(mx, __shfl_xor(mx, off));
    float sm = 0.f;
#pragma unroll
    for (int t = 0; t < 16; ++t) { ev[t][r] = __expf(S[t][r] - mx); sm += ev[t][r]; }
#pragma unroll
    for (int off = 1; off < 16; off <<= 1) sm += __shfl_xor(sm, off);
    rinv[r] = 1.0f / sm;
  }
  __syncthreads();
#pragma unroll
  for (int t = 0; t < 16; ++t)
#pragma unroll
    for (int r = 0; r < 4; ++r)
      bufB[(16 * w + 4 * lq + r) * 264 + 16 * t + lm] = f2bf(ev[t][r]);
  {
    const ush* tb = ttT + (size_t)bh * HD * NLM;
#pragma unroll
    for (int u = 0; u < 8; ++u) {
      int e8 = u * 256 + tid;
      int row = e8 >> 5, col = (e8 & 31) * 8;
      *(us8*)&bufA[row * 264 + col] = *(const us8*)&tb[row * NLM + col];
    }
  }
  __syncthreads();
  ffrag O[4] = {fz, fz, fz, fz};
#pragma unroll
  for (int kk = 0; kk < 8; ++kk) {
    bfrag a = *(const bfrag*)&bufB[(16 * w + lm) * 264 + 32 * kk + 8 * lq];
#pragma unroll
    for (int t2 = 0; t2 < 4; ++t2) {
      bfrag bb = *(const bfrag*)&bufA[(16 * t2 + lm) * 264 + 32 * kk + 8 * lq];
      O[t2] = __builtin_amdgcn_mfma_f32_16x16x32_bf16(a, bb, O[t2], 0, 0, 0);
    }
  }
#pragma unroll
  for (int t2 = 0; t2 < 4; ++t2)
#pragma unroll
    for (int r = 0; r < 4; ++r) {
      int i = i0 + 16 * w + 4 * lq + r;
      int d = 16 * t2 + lm;
      outp[((size_t)b * SEQ + i) * DIMC + h * HD + d] = O[t2][r] * rinv[r];
    }
}

// ---------------------------------------------------------------------------
// K9: conv add + split: outp(fp32) + depthwise conv(vT) -> outph/outpl
// ---------------------------------------------------------------------------
__global__ __launch_bounds__(256) void conv_add_split(const float* __restrict__ outp,
                                                      const ush* __restrict__ vT,
                                                      const float* __restrict__ kern,
                                                      ush* __restrict__ oh,
                                                      ush* __restrict__ ol) {
  __shared__ float vt[64 * 97];   // [d][96+1], cols n0-16 .. n0+79
  __shared__ float ks[KWIN];
  const int bh = blockIdx.y;
  const int b = bh >> 3, hh = bh & 7;
  const int n0 = blockIdx.x * 64;
  const int tid = threadIdx.x;
  if (tid < KWIN) ks[tid] = kern[hh * KWIN + tid];
  for (int e = tid; e < 64 * 96; e += 256) {
    int d = e / 96, c = e % 96;
    int n = n0 - 16 + c;
    vt[d * 97 + c] = (n >= 0 && n < SEQ) ? bf2f(vT[((size_t)bh * HD + d) * SEQ + n]) : 0.f;
  }
  __syncthreads();
  const int d = tid & 63, g = tid >> 6;
  float wreg[48];
#pragma unroll
  for (int j = 0; j < 48; ++j) wreg[j] = vt[d * 97 + g * 16 + j];
#pragma unroll
  for (int nn = 0; nn < 16; ++nn) {
    float s = 0.f;
#pragma unroll
    for (int t = 0; t < KWIN; ++t) s = fmaf(ks[t], wreg[nn + t], s);
    int n = n0 + g * 16 + nn;
    size_t o = ((size_t)b * SEQ + n) * DIMC + hh * HD + d;
    float val = outp[o] + s;
    ush h, l; splitf(val, h, l);
    oh[o] = h; ol[o] = l;
  }
}

// ---------------------------------------------------------------------------
// K10: out = outp_split @ WoutT_split + bias (3-product: final projection is
// precision-critical, keep full split). BM=BN=128, grid (128, 4)
// ---------------------------------------------------------------------------
__global__ __launch_bounds__(256) void out_gemm_split(const ush* __restrict__ ah_g,
                                                      const ush* __restrict__ al_g,
                                                      const ush* __restrict__ bh_g,
                                                      const ush* __restrict__ bl_g,
                                                      const float* __restrict__ bias,
                                                      float* __restrict__ out) {
  __shared__ ush Ash[128][40], Asl[128][40];
  __shared__ ush Bsh[128][40], Bsl[128][40];
  const int tid = threadIdx.x;
  const int w = tid >> 6, lane = tid & 63;
  const int lm = lane & 15, lq = lane >> 4;
  const int wm = w >> 1, wn = w & 1;
  const int row0 = blockIdx.x * 128, col0 = blockIdx.y * 128;
  const ffrag fz = {0.f, 0.f, 0.f, 0.f};
  ffrag acc[4][4];
#pragma unroll
  for (int i = 0; i < 4; ++i)
#pragma unroll
    for (int j = 0; j < 4; ++j) acc[i][j] = fz;

  const int sm = tid >> 1, skoff = (tid & 1) * 16;
  for (int k0 = 0; k0 < 512; k0 += 32) {
    __syncthreads();
    {
      size_t ao = (size_t)(row0 + sm) * 512 + k0 + skoff;
      *(us8*)&Ash[sm][skoff]     = *(const us8*)&ah_g[ao];
      *(us8*)&Ash[sm][skoff + 8] = *(const us8*)&ah_g[ao + 8];
      *(us8*)&Asl[sm][skoff]     = *(const us8*)&al_g[ao];
      *(us8*)&Asl[sm][skoff + 8] = *(const us8*)&al_g[ao + 8];
      size_t bo = (size_t)(col0 + sm) * 512 + k0 + skoff;
      *(us8*)&Bsh[sm][skoff]     = *(const us8*)&bh_g[bo];
      *(us8*)&Bsh[sm][skoff + 8] = *(const us8*)&bh_g[bo + 8];
      *(us8*)&Bsl[sm][skoff]     = *(const us8*)&bl_g[bo];
      *(us8*)&Bsl[sm][skoff + 8] = *(const us8*)&bl_g[bo + 8];
    }
    __syncthreads();
    bfrag ah[4], al[4], bh[4], bl[4];
#pragma unroll
    for (int mt = 0; mt < 4; ++mt) {
      ah[mt] = *(const bfrag*)&Ash[64 * wm + 16 * mt + lm][8 * lq];
      al[mt] = *(const bfrag*)&Asl[64 * wm + 16 * mt + lm][8 * lq];
    }
#pragma unroll
    for (int nt = 0; nt < 4; ++nt) {
      bh[nt] = *(const bfrag*)&Bsh[64 * wn + 16 * nt + lm][8 * lq];
      bl[nt] = *(const bfrag*)&Bsl[64 * wn + 16 * nt + lm][8 * lq];
    }
#pragma unroll
    for (int mt = 0; mt < 4; ++mt)
#pragma unroll
      for (int nt = 0; nt < 4; ++nt) {
        acc[mt][nt] = __builtin_amdgcn_mfma_f32_16x16x32_bf16(ah[mt], bh[nt], acc[mt][nt], 0, 0, 0);
        acc[mt][nt] = __builtin_amdgcn_mfma_f32_16x16x32_bf16(al[mt], bh[nt], acc[mt][nt], 0, 0, 0);
        acc[mt][nt] = __builtin_amdgcn_mfma_f32_16x16x32_bf16(ah[mt], bl[nt], acc[mt][nt], 0, 0, 0);
      }
  }
#pragma unroll
  for (int mt = 0; mt < 4; ++mt)
#pragma unroll
    for (int nt = 0; nt < 4; ++nt) {
      int n = col0 + 64 * wn + 16 * nt + lm;
      float bv = bias[n];
#pragma unroll
      for (int r = 0; r < 4; ++r) {
        int m = row0 + 64 * wm + 16 * mt + 4 * lq + r;
        out[(size_t)m * 512 + n] = acc[mt][nt][r] + bv;
      }
    }
}

// ---------------------------------------------------------------------------
extern "C" void kernel_launch(void* const* d_in, const int* in_sizes, int n_in,
                              void* d_out, int out_size, void* d_ws, size_t ws_size,
                              hipStream_t stream) {
  const float* x    = (const float*)d_in[0];
  const float* Wqkv = (const float*)d_in[1];
  const float* Wout = (const float*)d_in[2];
  const float* bout = (const float*)d_in[3];
  const float* rker = (const float*)d_in[4];
  float* out = (float*)d_out;
  float* ws = (float*)d_ws;

  // workspace layout (float-element offsets), total ~186.6 MB
  ush*   vT     = (ush*)(ws);                          // 8388608 ush (v transposed)
  ush*   q_bf   = (ush*)(ws + 4194304);                // 8388608 ush
  float* regA   = ws + 8388608;                        // 8388608 f: k_bf -> outp
  float* regB   = ws + 16777216;                       // 8388608 f: xh+xl -> outph+outpl
  float* qlm    = ws + 25165824;                       // 524288
  float* klm    = ws + 25690112;                       // 524288
  float* regC   = ws + 26214400;                       // 2097152 f: t2(h,l) / ttT
  float* a2reg  = ws + 28311552;                       // 2097152 f: a2h+a2l
  float* zAreg  = ws + 30408704;                       // 4194304 f
  float* zBreg  = ws + 34603008;                       // 4194304 f
  float* xzreg  = ws + 38797312;                       // 4194304 f: Y ping-pong (later O_part/l_part)
  float* t3reg  = ws + 43515904;                       // 2097152 f: U + Y2 (later svB)
  float* wqkvT  = ws + 45613056;                       // 786432 f
  float* woutT  = ws + 46399488;                       // 262144 f
  float* red    = ws + 46661632;                       // 128

  ush* k_bf  = (ush*)regA;
  float* outp = regA;
  ush* xh = (ush*)regB;                 // 8388608 ush
  ush* xl = (ush*)(regB + 4194304);     // 8388608 ush
  ush* outph = (ush*)regB;
  ush* outpl = (ush*)(regB + 4194304);
  ush* a2h = (ush*)a2reg;               // 2097152 ush each
  ush* a2l = (ush*)(a2reg + 1048576);
  ush* zA_[4] = {(ush*)zAreg, (ush*)(zAreg + 1048576), (ush*)(zAreg + 2097152), (ush*)(zAreg + 3145728)};
  ush* zB_[4] = {(ush*)zBreg, (ush*)(zBreg + 1048576), (ush*)(zBreg + 2097152), (ush*)(zBreg + 3145728)};
  ush* Y_h  = (ush*)xzreg;              // Y ping-pong (hi); lo slot doubles as ping B
  ush* Y_l  = (ush*)(xzreg + 1048576);  //   during plain carry-Y iters (lo dead)
  ush* t2_h = (ush*)regC;               // t2 = 7Y - Y^2, symmetric (row-major)
  ush* t2_l = (ush*)(regC + 1048576);
  ush* U_h  = (ush*)t3reg;              // U = z@Y (row-major)
  ush* U_l  = (ush*)(t3reg + 1048576);  // split iters: U lo; plain iters: Y2
  ush* Y2_h = U_l;                      // Y^2 (raw C tap) during plain iters
  float* O_part = xzreg;                // after pinv
  float* l_part = xzreg + 2097152;
  ush* svB_h = (ush*)t3reg;             // after pinv
  ush* svB_l = (ush*)(t3reg + 262144);
  ush* ttT   = (ush*)regC;              // after pinv
  ush* wqkvT_h = (ush*)wqkvT;
  ush* wqkvT_l = (ush*)(wqkvT + 393216);
  ush* woutT_h = (ush*)woutT;
  ush* woutT_l = (ush*)(woutT + 131072);

  // --- pre-splits ---
  split_flat<<<2048, 256, 0, stream>>>(x, xh, xl, 2097152);
  transpose_split_w2<<<dim3(48, 16, 2), 256, 0, stream>>>(
      Wqkv, wqkvT_h, wqkvT_l, 1536, Wout, woutT_h, woutT_l, 512);

  // --- qkv + landmarks (+ direct vT) ---
  qkv_mfma<<<dim3(128, 12), 256, 0, stream>>>(xh, xl, wqkvT_h,
                                              q_bf, k_bf, vT, qlm, klm);

  // --- attn2 + pinv init (finalize_scale launch removed: colmax atomicMax) ---
  sim2_softmax<<<8192, 256, 0, stream>>>(qlm, klm, a2h, a2l, red);
  colmax<<<32, 256, 0, stream>>>(a2h, red);
  zinit_split<<<dim3(8, 8, 32), 256, 0, stream>>>(a2h, a2l, red,
                                                  zA_[0], zA_[1], zA_[2], zA_[3]);

  // --- pinv Newton-Schulz (launch-synchronized; r4/r5: never re-fuse) ---
  // Plain iters 0-3: carry-Y, 2 launches/iter (depth-minimum, r7-r9 verified).
  // Iters 4-5: proven 3-stage split path, Y recomputed fresh from a2@z.
  ush** zc = zA_;
  ush** zn = zB_;
  ush* Yc = Y_h;
  ush* Yn = Y_l;   // lo slot dead during plain iters -> Y ping B
  // Y0 = a2 @ z0 (plain)
  bgemm_split<<<dim3(4, 4, 32), 256, 0, stream>>>(
      a2h, nullptr, zc[2], nullptr,
      nullptr, nullptr, nullptr, nullptr,
      Yc, nullptr, nullptr, nullptr,
      256, 256, 256, 0.f, 0.f, -1.f);
  for (int it = 0; it < 4; ++it) {
    ns_sa<<<dim3(4, 4, 64), 256, 0, stream>>>(Yc, zc[0], t2_h, Y2_h, U_h);
    ns_sb<<<dim3(4, 4, 64), 256, 0, stream>>>(zc[0], U_h, t2_h, Yc, Y2_h,
                                              zn[0], zn[2], Yn);
    ush** tp = zc; zc = zn; zn = tp;
    ush* ty = Yc; Yc = Yn; Yn = ty;
  }
  for (int it = 4; it < 6; ++it) {
    const bool zin_s = (it == 5);
    // S1: Y = a2 @ z (full split, fresh consistency)
    bgemm_split<<<dim3(4, 4, 32), 256, 0, stream>>>(
        a2h, a2l, zc[2], zin_s ? zc[3] : nullptr,
        nullptr, nullptr, nullptr, nullptr,
        Y_h, Y_l, nullptr, nullptr,
        256, 256, 256, 0.f, 0.f, -1.f);
    // S2: t2 = 7Y - Y@Y ; U = z@Y
    ns_s2<<<dim3(4, 4, 64), 256, 0, stream>>>(
        Y_h, Y_l, zc[0], zin_s ? zc[1] : nullptr,
        t2_h, t2_l, U_h, U_l);
    // S3: z' = 0.25*(13 z - 15 U + U@t2)
    bgemm_split<<<dim3(4, 4, 32), 256, 0, stream>>>(
        U_h, U_l, t2_h, t2_l,
        zc[0], zin_s ? zc[1] : nullptr,
        U_h, U_l,
        zn[0], zn[1], zn[2], zn[3],
        256, 256, 256, -13.f, 15.f, -0.25f);
    ush** tp = zc; zc = zn; zn = tp;
  }
  // after 6 swaps zc == zA_ (attn2_inv, full split)

  // --- sim3 (flash) ---
  sim3_mfma<<<dim3(4, NCH, 32), 256, 0, stream>>>(qlm, k_bf, vT, O_part, l_part);
  sim3_finalize<<<dim3(8, 32), 256, 0, stream>>>(O_part, l_part, svB_h, svB_l);

  // --- tt = attn2_inv @ sv (write ttT = tt^T plain bf16) ---
  bgemm_split<<<dim3(4, 1, 32), 256, 0, stream>>>(
      zc[0], zc[1], svB_h, svB_l,
      nullptr, nullptr, nullptr, nullptr,
      nullptr, nullptr, ttT, nullptr, 256, 64, 256, 0.f, 0.f, -1.f);

  // --- attn1 + conv + output projection ---
  attn1_mfma<<<dim3(64, 32), 256, 0, stream>>>(q_bf, klm, ttT, outp);
  conv_add_split<<<dim3(64, 32), 256, 0, stream>>>(outp, vT, rker, outph, outpl);
  out_gemm_split<<<dim3(128, 4), 256, 0, stream>>>(outph, outpl, woutT_h, woutT_l, bout, out);
}